// Round 8
// baseline (565.676 us; speedup 1.0000x reference)
//
#include <hip/hip_runtime.h>
#include <hip/hip_fp16.h>
#include <math.h>

#define TPB 256

struct alignas(8)  h2x2 { __half2 a, b; };
struct alignas(16) h2x4 { __half2 a, b, c, d; };

typedef _Float16 f16;
typedef __attribute__((ext_vector_type(8))) _Float16 f16x8;
typedef __attribute__((ext_vector_type(4))) float f32x4;

#define MFMA16(a, b, c) __builtin_amdgcn_mfma_f32_16x16x32_f16(a, b, c, 0, 0, 0)

// ---------------- per-node degree histogram (global atomics, L2-resident counters) ----------------
__global__ void __launch_bounds__(256) k_nhist(const int* __restrict__ dst,
                                               int* __restrict__ counts, int E) {
  int stride = gridDim.x * TPB;
  for (int i = blockIdx.x * TPB + threadIdx.x; i < E; i += stride)
    atomicAdd(&counts[__builtin_nontemporal_load(&dst[i])], 1);
}

// ---------------- scan (1024 items/block) ----------------
__global__ void k_scan_block(const int* __restrict__ deg, int* __restrict__ offs,
                             int* __restrict__ bsums, int n) {
  __shared__ int lds[256];
  int t = threadIdx.x, b = blockIdx.x;
  int base = b * 1024 + t * 4;
  int v0 = (base + 0 < n) ? deg[base + 0] : 0;
  int v1 = (base + 1 < n) ? deg[base + 1] : 0;
  int v2 = (base + 2 < n) ? deg[base + 2] : 0;
  int v3 = (base + 3 < n) ? deg[base + 3] : 0;
  int s = v0 + v1 + v2 + v3;
  lds[t] = s;
  __syncthreads();
  int acc = s;
  for (int off = 1; off < 256; off <<= 1) {
    int x = (t >= off) ? lds[t - off] : 0;
    __syncthreads();
    acc += x;
    lds[t] = acc;
    __syncthreads();
  }
  int excl = acc - s;
  if (base + 0 < n) offs[base + 0] = excl;
  if (base + 1 < n) offs[base + 1] = excl + v0;
  if (base + 2 < n) offs[base + 2] = excl + v0 + v1;
  if (base + 3 < n) offs[base + 3] = excl + v0 + v1 + v2;
  if (t == 255) bsums[b] = acc;
}

__global__ void k_scan_mid(int* __restrict__ bsums, int nb) {
  __shared__ int lds[256];
  int t = threadIdx.x;
  int v = (t < nb) ? bsums[t] : 0;
  lds[t] = v;
  __syncthreads();
  int acc = v;
  for (int off = 1; off < 256; off <<= 1) {
    int x = (t >= off) ? lds[t - off] : 0;
    __syncthreads();
    acc += x;
    lds[t] = acc;
    __syncthreads();
  }
  if (t < nb) bsums[t] = acc - v;  // exclusive
}

__global__ void k_scan_add(int* __restrict__ offs, const int* __restrict__ bsums,
                           int n, int total) {
  int t = threadIdx.x, b = blockIdx.x;
  int add = bsums[b];
  int base = b * 1024 + t * 4;
#pragma unroll
  for (int j = 0; j < 4; ++j)
    if (base + j < n) offs[base + j] += add;
  if (b == 0 && t == 0) offs[n] = total;
}

// ---------------- direct CSR fill: one scattered-store pass ----------------
// pos = noffs[d] + cnt[d]++ (global atomic). Replaces the old bin-fill + per-bin
// counting sort (two scattered passes + ebuf round-trip). Order within a node is
// nondeterministic -> fp sum rounding differs at ~1e-7 (absmax dominated by fp16 h1).
__global__ void __launch_bounds__(256) k_fill(const int* __restrict__ src,
                                              const int* __restrict__ dst,
                                              const float* __restrict__ attr,
                                              const int* __restrict__ noffs,
                                              int* __restrict__ cnt,
                                              int2* __restrict__ csr, int E) {
  int stride = gridDim.x * TPB;
  for (int i = blockIdx.x * TPB + threadIdx.x; i < E; i += stride) {
    int d = __builtin_nontemporal_load(&dst[i]);
    int sv = __builtin_nontemporal_load(&src[i]);
    float av = __builtin_nontemporal_load(&attr[i]);
    int pos = noffs[d] + atomicAdd(&cnt[d], 1);
    csr[pos] = make_int2(sv, __float_as_int(av));
  }
}

// ---------------- Layer-1 aggregation: 16 threads/node, f<9 active ----------------
// Predicated 8-edge passes (8 csr + 8 x-gathers in flight).
__global__ void __launch_bounds__(256) k_agg1(
    const float* __restrict__ x, const int2* __restrict__ csr,
    const int* __restrict__ noffs, const float* __restrict__ We1,
    const float* __restrict__ be1, float* __restrict__ u1, int N) {
  int t = blockIdx.x * TPB + threadIdx.x;
  int node = t >> 4, f = t & 15;
  if (node >= N || f >= 9) return;
  int o0 = noffs[node], o1 = noffs[node + 1];
  float we = We1[f], be = be1[f];
  float acc = 0.f;
  int last = o1 - 1;
  for (int e = o0; e < o1; e += 8) {
    int i0 = e;     bool m0 = i0 < o1; i0 = m0 ? i0 : last;
    int i1 = e + 1; bool m1 = i1 < o1; i1 = m1 ? i1 : last;
    int i2 = e + 2; bool m2 = i2 < o1; i2 = m2 ? i2 : last;
    int i3 = e + 3; bool m3 = i3 < o1; i3 = m3 ? i3 : last;
    int i4 = e + 4; bool m4 = i4 < o1; i4 = m4 ? i4 : last;
    int i5 = e + 5; bool m5 = i5 < o1; i5 = m5 ? i5 : last;
    int i6 = e + 6; bool m6 = i6 < o1; i6 = m6 ? i6 : last;
    int i7 = e + 7; bool m7 = i7 < o1; i7 = m7 ? i7 : last;
    int2 p0 = csr[i0], p1 = csr[i1], p2 = csr[i2], p3 = csr[i3];
    int2 p4 = csr[i4], p5 = csr[i5], p6 = csr[i6], p7 = csr[i7];
    float v0 = x[p0.x * 9 + f] + fmaf(__int_as_float(p0.y), we, be);
    float v1 = x[p1.x * 9 + f] + fmaf(__int_as_float(p1.y), we, be);
    float v2 = x[p2.x * 9 + f] + fmaf(__int_as_float(p2.y), we, be);
    float v3 = x[p3.x * 9 + f] + fmaf(__int_as_float(p3.y), we, be);
    float v4 = x[p4.x * 9 + f] + fmaf(__int_as_float(p4.y), we, be);
    float v5 = x[p5.x * 9 + f] + fmaf(__int_as_float(p5.y), we, be);
    float v6 = x[p6.x * 9 + f] + fmaf(__int_as_float(p6.y), we, be);
    float v7 = x[p7.x * 9 + f] + fmaf(__int_as_float(p7.y), we, be);
    acc += m0 ? fmaxf(v0, 0.f) : 0.f;
    acc += m1 ? fmaxf(v1, 0.f) : 0.f;
    acc += m2 ? fmaxf(v2, 0.f) : 0.f;
    acc += m3 ? fmaxf(v3, 0.f) : 0.f;
    acc += m4 ? fmaxf(v4, 0.f) : 0.f;
    acc += m5 ? fmaxf(v5, 0.f) : 0.f;
    acc += m6 ? fmaxf(v6, 0.f) : 0.f;
    acc += m7 ? fmaxf(v7, 0.f) : 0.f;
  }
  u1[node * 9 + f] = x[node * 9 + f] + acc;
}

// ---------------- Layer-2 aggregation: one wave/node; 8 edge-slots x 8 feature-chunks ----------------
// Two-tier predicated schedule (8-deep while >32 remain, 4-deep final), SCALAR f32 math.
// R6 lesson: packed f32x2 pushed VGPR 44->68, over the 64-VGPR occupancy cliff -> 144us.
// Keep VGPR < 64 here at all costs; occupancy >= issue-count for this kernel.
__global__ void __launch_bounds__(256) k_agg2(
    const __half* __restrict__ h1, const long long* __restrict__ csr,
    const int* __restrict__ noffs, const float* __restrict__ We2,
    const float* __restrict__ be2, float* __restrict__ u2, int N) {
  int gt = blockIdx.x * TPB + threadIdx.x;
  int node = gt >> 6;
  if (node >= N) return;
  int lane = gt & 63;
  int q = lane >> 3, c = lane & 7;
  float4 weA = *(const float4*)&We2[c * 8];
  float4 weB = *(const float4*)&We2[c * 8 + 4];
  float4 beA = *(const float4*)&be2[c * 8];
  float4 beB = *(const float4*)&be2[c * 8 + 4];
  int o0 = noffs[node], o1 = noffs[node + 1];
  float a0 = 0.f, a1 = 0.f, a2 = 0.f, a3 = 0.f, a4 = 0.f, a5 = 0.f, a6 = 0.f, a7 = 0.f;

#define AGG2_ACCM(pv, v, m)                                                  \
  {                                                                          \
    float ea = __int_as_float((int)(unsigned int)(((unsigned long long)(pv)) >> 32)); \
    float2 f0 = __half22float2((v).a), f1 = __half22float2((v).b);           \
    float2 f2 = __half22float2((v).c), f3 = __half22float2((v).d);           \
    a0 += (m) ? fmaxf(f0.x + fmaf(ea, weA.x, beA.x), 0.f) : 0.f;             \
    a1 += (m) ? fmaxf(f0.y + fmaf(ea, weA.y, beA.y), 0.f) : 0.f;             \
    a2 += (m) ? fmaxf(f1.x + fmaf(ea, weA.z, beA.z), 0.f) : 0.f;             \
    a3 += (m) ? fmaxf(f1.y + fmaf(ea, weA.w, beA.w), 0.f) : 0.f;             \
    a4 += (m) ? fmaxf(f2.x + fmaf(ea, weB.x, beB.x), 0.f) : 0.f;             \
    a5 += (m) ? fmaxf(f2.y + fmaf(ea, weB.y, beB.y), 0.f) : 0.f;             \
    a6 += (m) ? fmaxf(f3.x + fmaf(ea, weB.z, beB.z), 0.f) : 0.f;             \
    a7 += (m) ? fmaxf(f3.y + fmaf(ea, weB.w, beB.w), 0.f) : 0.f;             \
  }

  int e = o0;
  // 8-deep passes while more than one 32-edge tier remains
  if (o1 - e > 32) {
    int last = o1 - 1;
    do {
      long long pv0, pv1, pv2, pv3, pv4, pv5, pv6, pv7;
      bool m0, m1, m2, m3, m4, m5, m6, m7;
      {
        int i0 = e + q;      m0 = i0 < o1; i0 = m0 ? i0 : last;
        int i1 = e + 8 + q;  m1 = i1 < o1; i1 = m1 ? i1 : last;
        int i2 = e + 16 + q; m2 = i2 < o1; i2 = m2 ? i2 : last;
        int i3 = e + 24 + q; m3 = i3 < o1; i3 = m3 ? i3 : last;
        int i4 = e + 32 + q; m4 = i4 < o1; i4 = m4 ? i4 : last;
        int i5 = e + 40 + q; m5 = i5 < o1; i5 = m5 ? i5 : last;
        int i6 = e + 48 + q; m6 = i6 < o1; i6 = m6 ? i6 : last;
        int i7 = e + 56 + q; m7 = i7 < o1; i7 = m7 ? i7 : last;
        pv0 = __builtin_nontemporal_load(&csr[i0]);
        pv1 = __builtin_nontemporal_load(&csr[i1]);
        pv2 = __builtin_nontemporal_load(&csr[i2]);
        pv3 = __builtin_nontemporal_load(&csr[i3]);
        pv4 = __builtin_nontemporal_load(&csr[i4]);
        pv5 = __builtin_nontemporal_load(&csr[i5]);
        pv6 = __builtin_nontemporal_load(&csr[i6]);
        pv7 = __builtin_nontemporal_load(&csr[i7]);
      }
      h2x4 v0 = *(const h2x4*)(h1 + (size_t)(int)(unsigned int)(pv0 & 0xffffffffLL) * 64 + c * 8);
      h2x4 v1 = *(const h2x4*)(h1 + (size_t)(int)(unsigned int)(pv1 & 0xffffffffLL) * 64 + c * 8);
      h2x4 v2 = *(const h2x4*)(h1 + (size_t)(int)(unsigned int)(pv2 & 0xffffffffLL) * 64 + c * 8);
      h2x4 v3 = *(const h2x4*)(h1 + (size_t)(int)(unsigned int)(pv3 & 0xffffffffLL) * 64 + c * 8);
      h2x4 v4 = *(const h2x4*)(h1 + (size_t)(int)(unsigned int)(pv4 & 0xffffffffLL) * 64 + c * 8);
      h2x4 v5 = *(const h2x4*)(h1 + (size_t)(int)(unsigned int)(pv5 & 0xffffffffLL) * 64 + c * 8);
      h2x4 v6 = *(const h2x4*)(h1 + (size_t)(int)(unsigned int)(pv6 & 0xffffffffLL) * 64 + c * 8);
      h2x4 v7 = *(const h2x4*)(h1 + (size_t)(int)(unsigned int)(pv7 & 0xffffffffLL) * 64 + c * 8);
      AGG2_ACCM(pv0, v0, m0); AGG2_ACCM(pv1, v1, m1);
      AGG2_ACCM(pv2, v2, m2); AGG2_ACCM(pv3, v3, m3);
      AGG2_ACCM(pv4, v4, m4); AGG2_ACCM(pv5, v5, m5);
      AGG2_ACCM(pv6, v6, m6); AGG2_ACCM(pv7, v7, m7);
      e += 64;
    } while (o1 - e > 32);
  }
  // final tier: <=32 edges, 4-deep predicated
  if (e < o1) {
    int last = o1 - 1;
    int i0 = e + q;      bool m0 = i0 < o1; i0 = m0 ? i0 : last;
    int i1 = e + 8 + q;  bool m1 = i1 < o1; i1 = m1 ? i1 : last;
    int i2 = e + 16 + q; bool m2 = i2 < o1; i2 = m2 ? i2 : last;
    int i3 = e + 24 + q; bool m3 = i3 < o1; i3 = m3 ? i3 : last;
    long long pv0 = __builtin_nontemporal_load(&csr[i0]);
    long long pv1 = __builtin_nontemporal_load(&csr[i1]);
    long long pv2 = __builtin_nontemporal_load(&csr[i2]);
    long long pv3 = __builtin_nontemporal_load(&csr[i3]);
    h2x4 v0 = *(const h2x4*)(h1 + (size_t)(int)(unsigned int)(pv0 & 0xffffffffLL) * 64 + c * 8);
    h2x4 v1 = *(const h2x4*)(h1 + (size_t)(int)(unsigned int)(pv1 & 0xffffffffLL) * 64 + c * 8);
    h2x4 v2 = *(const h2x4*)(h1 + (size_t)(int)(unsigned int)(pv2 & 0xffffffffLL) * 64 + c * 8);
    h2x4 v3 = *(const h2x4*)(h1 + (size_t)(int)(unsigned int)(pv3 & 0xffffffffLL) * 64 + c * 8);
    AGG2_ACCM(pv0, v0, m0); AGG2_ACCM(pv1, v1, m1);
    AGG2_ACCM(pv2, v2, m2); AGG2_ACCM(pv3, v3, m3);
  }
#undef AGG2_ACCM

  a0 += __shfl_xor(a0, 8, 64); a0 += __shfl_xor(a0, 16, 64); a0 += __shfl_xor(a0, 32, 64);
  a1 += __shfl_xor(a1, 8, 64); a1 += __shfl_xor(a1, 16, 64); a1 += __shfl_xor(a1, 32, 64);
  a2 += __shfl_xor(a2, 8, 64); a2 += __shfl_xor(a2, 16, 64); a2 += __shfl_xor(a2, 32, 64);
  a3 += __shfl_xor(a3, 8, 64); a3 += __shfl_xor(a3, 16, 64); a3 += __shfl_xor(a3, 32, 64);
  a4 += __shfl_xor(a4, 8, 64); a4 += __shfl_xor(a4, 16, 64); a4 += __shfl_xor(a4, 32, 64);
  a5 += __shfl_xor(a5, 8, 64); a5 += __shfl_xor(a5, 16, 64); a5 += __shfl_xor(a5, 32, 64);
  a6 += __shfl_xor(a6, 8, 64); a6 += __shfl_xor(a6, 16, 64); a6 += __shfl_xor(a6, 32, 64);
  a7 += __shfl_xor(a7, 8, 64); a7 += __shfl_xor(a7, 16, 64); a7 += __shfl_xor(a7, 32, 64);

  if (q == 0) {
    h2x4 sf = *(const h2x4*)(h1 + (size_t)node * 64 + c * 8);
    float2 s0 = __half22float2(sf.a), s1 = __half22float2(sf.b);
    float2 s2 = __half22float2(sf.c), s3 = __half22float2(sf.d);
    float4 oA, oB;
    oA.x = s0.x + a0; oA.y = s0.y + a1; oA.z = s1.x + a2; oA.w = s1.y + a3;
    oB.x = s2.x + a4; oB.y = s2.y + a5; oB.z = s3.x + a6; oB.w = s3.y + a7;
    *(float4*)&u2[(size_t)node * 64 + c * 8] = oA;
    *(float4*)&u2[(size_t)node * 64 + c * 8 + 4] = oB;
  }
}

// ---------------- split-fp16 helpers for MFMA (f32-class accuracy) ----------------
__device__ __forceinline__ void splitf8(const float* v, f16x8& h, f16x8& l) {
#pragma unroll
  for (int j = 0; j < 8; ++j) {
    float x = v[j];
    f16 hh = (f16)x;
    h[j] = hh;
    l[j] = (f16)(x - (float)hh);
  }
}

// pack W [K][Nout] row-major into per-lane MFMA B-fragments (hi/lo planes).
__device__ __forceinline__ void pack_w(const float* __restrict__ W, int Ntiles, int nslots,
                                       f16* hi, f16* lo, int t) {
  int lane = t & 63;
  int kg = lane >> 4, m = lane & 15;
  int Nout = Ntiles * 16;
  for (int s = t >> 6; s < nslots; s += 4) {
    int ks = s / Ntiles, nt = s - ks * Ntiles;
    int kbase = ks * 32 + kg * 8;
    int n = nt * 16 + m;
    float v[8];
#pragma unroll
    for (int j = 0; j < 8; ++j) v[j] = W[(kbase + j) * Nout + n];
    f16x8 h, l;
    splitf8(v, h, l);
    *(f16x8*)&hi[(s * 64 + lane) * 8] = h;
    *(f16x8*)&lo[(s * 64 + lane) * 8] = l;
  }
}

// ---------------- Layer-1 MLP (9->64->64) via split-fp16 MFMA, fp16 output ----------------
__global__ void __launch_bounds__(256) k_mlp9(
    const float* __restrict__ uin, const float* __restrict__ Wa,
    const float* __restrict__ ba, const float* __restrict__ Wb,
    const float* __restrict__ bb, __half* __restrict__ hout, int N) {
  __shared__ __align__(16) f16 wf1h[2048], wf1l[2048];
  __shared__ __align__(16) f16 wf2h[4096], wf2l[4096];
  __shared__ float ls_z[64 * 65];
  __shared__ float ls_ba[64], ls_bb[64];
  const int t = threadIdx.x;
  const int n0 = blockIdx.x * 64;
  const int w = t >> 6, lane = t & 63;
  const int m = lane & 15, kg = lane >> 4;

  {
    int s = w;
    int n = s * 16 + m;
    float v[8];
#pragma unroll
    for (int j = 0; j < 8; ++j) {
      int k = kg * 8 + j;
      v[j] = (k < 9) ? Wa[k * 64 + n] : 0.f;
    }
    f16x8 h, l;
    splitf8(v, h, l);
    *(f16x8*)&wf1h[(s * 64 + lane) * 8] = h;
    *(f16x8*)&wf1l[(s * 64 + lane) * 8] = l;
  }
  pack_w(Wb, 4, 8, wf2h, wf2l, t);
  if (t < 64) { ls_ba[t] = ba[t]; ls_bb[t] = bb[t]; }
  __syncthreads();

  int row = min(n0 + w * 16 + m, N - 1);
  float av[8];
#pragma unroll
  for (int j = 0; j < 8; ++j) {
    int k = kg * 8 + j;
    av[j] = (k < 9) ? uin[(size_t)row * 9 + k] : 0.f;
  }
  f16x8 a0h, a0l, a1h, a1l;
  splitf8(av, a0h, a0l);

  f32x4 acc[4];
#pragma unroll
  for (int nt = 0; nt < 4; ++nt) { f32x4 z4 = {0.f, 0.f, 0.f, 0.f}; acc[nt] = z4; }
#pragma unroll
  for (int nt = 0; nt < 4; ++nt) {
    f16x8 bh = *(const f16x8*)&wf1h[(nt * 64 + lane) * 8];
    f16x8 bl = *(const f16x8*)&wf1l[(nt * 64 + lane) * 8];
    acc[nt] = MFMA16(a0h, bh, acc[nt]);
    acc[nt] = MFMA16(a0l, bh, acc[nt]);
    acc[nt] = MFMA16(a0h, bl, acc[nt]);
  }
#pragma unroll
  for (int nt = 0; nt < 4; ++nt)
#pragma unroll
    for (int r = 0; r < 4; ++r)
      ls_z[(w * 16 + kg * 4 + r) * 65 + nt * 16 + m] = fmaxf(acc[nt][r] + ls_ba[nt * 16 + m], 0.f);
  __syncthreads();

  const float* zr = &ls_z[(size_t)(w * 16 + m) * 65 + kg * 8];
  {
    float zv0[8], zv1[8];
#pragma unroll
    for (int j = 0; j < 8; ++j) { zv0[j] = zr[j]; zv1[j] = zr[32 + j]; }
    splitf8(zv0, a0h, a0l);
    splitf8(zv1, a1h, a1l);
  }
#pragma unroll
  for (int nt = 0; nt < 4; ++nt) { f32x4 z4 = {0.f, 0.f, 0.f, 0.f}; acc[nt] = z4; }
#pragma unroll
  for (int nt = 0; nt < 4; ++nt) {
#pragma unroll
    for (int ks = 0; ks < 2; ++ks) {
      int s = ks * 4 + nt;
      f16x8 bh = *(const f16x8*)&wf2h[(s * 64 + lane) * 8];
      f16x8 bl = *(const f16x8*)&wf2l[(s * 64 + lane) * 8];
      f16x8 ah = ks ? a1h : a0h;
      f16x8 al = ks ? a1l : a0l;
      acc[nt] = MFMA16(ah, bh, acc[nt]);
      acc[nt] = MFMA16(al, bh, acc[nt]);
      acc[nt] = MFMA16(ah, bl, acc[nt]);
    }
  }
#pragma unroll
  for (int nt = 0; nt < 4; ++nt)
#pragma unroll
    for (int r = 0; r < 4; ++r) {
      int node = n0 + w * 16 + kg * 4 + r;
      if (node < N)
        hout[(size_t)node * 64 + nt * 16 + m] =
            __float2half(fmaxf(acc[nt][r] + ls_bb[nt * 16 + m], 0.f));
    }
}

// ---------------- Layer-2 MLP (64->64->64) + readout via split-fp16 MFMA ----------------
__global__ void __launch_bounds__(256) k_mlp_ro(
    const float* __restrict__ uin, const float* __restrict__ Wa,
    const float* __restrict__ ba, const float* __restrict__ Wb,
    const float* __restrict__ bb, const float* __restrict__ Wr1,
    const float* __restrict__ br1, const float* __restrict__ Wr2,
    const float* __restrict__ br2, const int* __restrict__ tmask,
    float* __restrict__ pi, int N) {
  __shared__ __align__(16) f16 wf1h[4096], wf1l[4096];
  __shared__ __align__(16) f16 wf2h[4096], wf2l[4096];
  __shared__ __align__(16) f16 wfrh[2048], wfrl[2048];
  __shared__ float ls_z[64 * 65];
  __shared__ float ls_ba[64], ls_bb[64], ls_br1[32], ls_w2[32];
  const int t = threadIdx.x;
  const int n0 = blockIdx.x * 64;

  pack_w(Wa, 4, 8, wf1h, wf1l, t);
  pack_w(Wb, 4, 8, wf2h, wf2l, t);
  pack_w(Wr1, 2, 4, wfrh, wfrl, t);
  if (t < 64) { ls_ba[t] = ba[t]; ls_bb[t] = bb[t]; }
  else if (t < 96) { ls_br1[t - 64] = br1[t - 64]; ls_w2[t - 64] = Wr2[t - 64]; }
  __syncthreads();

  const int w = t >> 6, lane = t & 63;
  const int m = lane & 15, kg = lane >> 4;

  int row = n0 + w * 16 + m;
  row = min(row, N - 1);
  const float* ar = uin + (size_t)row * 64 + kg * 8;
  float av0[8], av1[8];
  {
    f32x4 p0 = *(const f32x4*)ar;
    f32x4 p1 = *(const f32x4*)(ar + 4);
    f32x4 p2 = *(const f32x4*)(ar + 32);
    f32x4 p3 = *(const f32x4*)(ar + 36);
#pragma unroll
    for (int j = 0; j < 4; ++j) {
      av0[j] = p0[j]; av0[4 + j] = p1[j];
      av1[j] = p2[j]; av1[4 + j] = p3[j];
    }
  }
  f16x8 a0h, a0l, a1h, a1l;
  splitf8(av0, a0h, a0l);
  splitf8(av1, a1h, a1l);

  f32x4 acc[4];
#pragma unroll
  for (int nt = 0; nt < 4; ++nt) { f32x4 z4 = {0.f, 0.f, 0.f, 0.f}; acc[nt] = z4; }
#pragma unroll
  for (int nt = 0; nt < 4; ++nt) {
#pragma unroll
    for (int ks = 0; ks < 2; ++ks) {
      int s = ks * 4 + nt;
      f16x8 bh = *(const f16x8*)&wf1h[(s * 64 + lane) * 8];
      f16x8 bl = *(const f16x8*)&wf1l[(s * 64 + lane) * 8];
      f16x8 ah = ks ? a1h : a0h;
      f16x8 al = ks ? a1l : a0l;
      acc[nt] = MFMA16(ah, bh, acc[nt]);
      acc[nt] = MFMA16(al, bh, acc[nt]);
      acc[nt] = MFMA16(ah, bl, acc[nt]);
    }
  }
#pragma unroll
  for (int nt = 0; nt < 4; ++nt)
#pragma unroll
    for (int r = 0; r < 4; ++r)
      ls_z[(w * 16 + kg * 4 + r) * 65 + nt * 16 + m] = fmaxf(acc[nt][r] + ls_ba[nt * 16 + m], 0.f);
  __syncthreads();

  const float* zr = &ls_z[(size_t)(w * 16 + m) * 65 + kg * 8];
  {
    float zv0[8], zv1[8];
#pragma unroll
    for (int j = 0; j < 8; ++j) { zv0[j] = zr[j]; zv1[j] = zr[32 + j]; }
    splitf8(zv0, a0h, a0l);
    splitf8(zv1, a1h, a1l);
  }
#pragma unroll
  for (int nt = 0; nt < 4; ++nt) { f32x4 z4 = {0.f, 0.f, 0.f, 0.f}; acc[nt] = z4; }
#pragma unroll
  for (int nt = 0; nt < 4; ++nt) {
#pragma unroll
    for (int ks = 0; ks < 2; ++ks) {
      int s = ks * 4 + nt;
      f16x8 bh = *(const f16x8*)&wf2h[(s * 64 + lane) * 8];
      f16x8 bl = *(const f16x8*)&wf2l[(s * 64 + lane) * 8];
      f16x8 ah = ks ? a1h : a0h;
      f16x8 al = ks ? a1l : a0l;
      acc[nt] = MFMA16(ah, bh, acc[nt]);
      acc[nt] = MFMA16(al, bh, acc[nt]);
      acc[nt] = MFMA16(ah, bl, acc[nt]);
    }
  }
  __syncthreads();
#pragma unroll
  for (int nt = 0; nt < 4; ++nt)
#pragma unroll
    for (int r = 0; r < 4; ++r)
      ls_z[(w * 16 + kg * 4 + r) * 65 + nt * 16 + m] = fmaxf(acc[nt][r] + ls_bb[nt * 16 + m], 0.f);
  __syncthreads();

  {
    float zv0[8], zv1[8];
#pragma unroll
    for (int j = 0; j < 8; ++j) { zv0[j] = zr[j]; zv1[j] = zr[32 + j]; }
    splitf8(zv0, a0h, a0l);
    splitf8(zv1, a1h, a1l);
  }
  f32x4 accr[2];
#pragma unroll
  for (int nt = 0; nt < 2; ++nt) { f32x4 z4 = {0.f, 0.f, 0.f, 0.f}; accr[nt] = z4; }
#pragma unroll
  for (int nt = 0; nt < 2; ++nt) {
#pragma unroll
    for (int ks = 0; ks < 2; ++ks) {
      int s = ks * 2 + nt;
      f16x8 bh = *(const f16x8*)&wfrh[(s * 64 + lane) * 8];
      f16x8 bl = *(const f16x8*)&wfrl[(s * 64 + lane) * 8];
      f16x8 ah = ks ? a1h : a0h;
      f16x8 al = ks ? a1l : a0l;
      accr[nt] = MFMA16(ah, bh, accr[nt]);
      accr[nt] = MFMA16(al, bh, accr[nt]);
      accr[nt] = MFMA16(ah, bl, accr[nt]);
    }
  }
  float b2 = br2[0];
#pragma unroll
  for (int r = 0; r < 4; ++r) {
    float v0 = fmaxf(accr[0][r] + ls_br1[m], 0.f) * ls_w2[m];
    float v1 = fmaxf(accr[1][r] + ls_br1[16 + m], 0.f) * ls_w2[16 + m];
    float tr = v0 + v1;
    tr += __shfl_xor(tr, 1, 64);
    tr += __shfl_xor(tr, 2, 64);
    tr += __shfl_xor(tr, 4, 64);
    tr += __shfl_xor(tr, 8, 64);
    if (m == 0) {
      int node = n0 + w * 16 + kg * 4 + r;
      if (node < N) {
        float sg = 1.f / (1.f + expf(-(tr + b2)));
        pi[node] = sg * (1.f - (float)tmask[node]);
      }
    }
  }
}

// ---------------- Group sums (batch sorted) ----------------
__global__ void k_grpsum(const float* __restrict__ pi, const float* __restrict__ c_cost,
                         const int* __restrict__ batch, float* __restrict__ exp_tot, int N) {
  __shared__ float lsf[256];
  __shared__ int lsi[256];
  int t = threadIdx.x;
  int i = blockIdx.x * TPB + t;
  bool valid = i < N;
  int g = valid ? batch[i] : 0;
  float v = valid ? pi[i] * c_cost[i] : 0.f;
  lsi[t] = valid ? g : 0x7fffffff;
  __syncthreads();
  for (int s = 128; s > 0; s >>= 1) { if (t < s) lsi[t] = min(lsi[t], lsi[t + s]); __syncthreads(); }
  int gmin = lsi[0];
  __syncthreads();
  lsi[t] = valid ? g : -1;
  __syncthreads();
  for (int s = 128; s > 0; s >>= 1) { if (t < s) lsi[t] = max(lsi[t], lsi[t + s]); __syncthreads(); }
  int gmax = lsi[0];
  __syncthreads();
  for (int gg = gmin; gg <= gmax; ++gg) {
    lsf[t] = (valid && g == gg) ? v : 0.f;
    __syncthreads();
    for (int s = 128; s > 0; s >>= 1) { if (t < s) lsf[t] += lsf[t + s]; __syncthreads(); }
    if (t == 0) atomicAdd(&exp_tot[gg], lsf[0]);
    __syncthreads();
  }
}

__global__ void k_final(const float* __restrict__ pi, const int* __restrict__ batch,
                        const float* __restrict__ B_total, const float* __restrict__ exp_tot,
                        float* __restrict__ out, int N) {
  int i = blockIdx.x * TPB + threadIdx.x;
  if (i < N) {
    int g = batch[i];
    float ratio = fminf(B_total[g] / (exp_tot[g] + 1e-12f), 1.f);
    out[i] = pi[i] * ratio;
  }
}

extern "C" void kernel_launch(void* const* d_in, const int* in_sizes, int n_in,
                              void* d_out, int out_size, void* d_ws, size_t ws_size,
                              hipStream_t stream) {
  const float* x     = (const float*)d_in[0];
  const int*   ei    = (const int*)d_in[1];
  const float* eattr = (const float*)d_in[2];
  const int*   batch = (const int*)d_in[3];
  const float* Btot  = (const float*)d_in[4];
  const int*   tmask = (const int*)d_in[5];
  const float* ccost = (const float*)d_in[6];
  const float* We1 = (const float*)d_in[7],  *be1 = (const float*)d_in[8];
  const float* W1a = (const float*)d_in[9],  *b1a = (const float*)d_in[10];
  const float* W1b = (const float*)d_in[11], *b1b = (const float*)d_in[12];
  const float* We2 = (const float*)d_in[13], *be2 = (const float*)d_in[14];
  const float* W2a = (const float*)d_in[15], *b2a = (const float*)d_in[16];
  const float* W2b = (const float*)d_in[17], *b2b = (const float*)d_in[18];
  const float* Wr1 = (const float*)d_in[19], *br1 = (const float*)d_in[20];
  const float* Wr2 = (const float*)d_in[21], *br2 = (const float*)d_in[22];
  float* out = (float*)d_out;

  const int N = in_sizes[0] / 9;
  const int E = in_sizes[2];
  const int G = in_sizes[4];
  const int* src = ei;
  const int* dst = ei + E;

  // workspace carve-up (4-byte elements)
  size_t cur = 0;
  auto alloc = [&](size_t elems) { size_t r = cur; cur += elems; cur = (cur + 63) & ~(size_t)63; return r; };
  char* wsb = (char*)d_ws;
  size_t o_exp    = alloc(G);              // zeroed
  size_t o_counts = alloc(N);              // degree histogram (zeroed)
  size_t o_cnt    = alloc(N);              // fill cursors (zeroed)
  size_t o_noffs  = alloc(N + 1);
  size_t o_bsums  = alloc(256);
  size_t o_csr    = alloc(2 * (size_t)E);
  size_t o_h1     = alloc((size_t)N * 32); // fp16 h1 (N*64 halves)
  size_t o_u1     = alloc((size_t)N * 9);
  size_t o_u2     = alloc((size_t)N * 64);
  size_t o_pi     = alloc(N);
  (void)ws_size;

  float* exp_t  = (float*)wsb + o_exp;
  int*   counts = (int*)wsb + o_counts;
  int*   cnt    = (int*)wsb + o_cnt;
  int*   noffs  = (int*)wsb + o_noffs;
  int*   bsums  = (int*)wsb + o_bsums;
  int2*  csr    = (int2*)((int*)wsb + o_csr);
  __half* h1h   = (__half*)((int*)wsb + o_h1);
  float* u1     = (float*)wsb + o_u1;
  float* u2     = (float*)wsb + o_u2;
  float* pi     = (float*)wsb + o_pi;

  (void)hipMemsetAsync(exp_t, 0, (size_t)G * 4, stream);
  (void)hipMemsetAsync(counts, 0, (size_t)N * 4, stream);
  (void)hipMemsetAsync(cnt, 0, (size_t)N * 4, stream);

  const int nb = (N + 1023) / 1024;

  k_nhist<<<1024, TPB, 0, stream>>>(dst, counts, E);
  k_scan_block<<<nb, TPB, 0, stream>>>(counts, noffs, bsums, N);
  k_scan_mid<<<1, 256, 0, stream>>>(bsums, nb);
  k_scan_add<<<nb, TPB, 0, stream>>>(noffs, bsums, N, E);
  k_fill<<<2048, TPB, 0, stream>>>(src, dst, eattr, noffs, cnt, csr, E);

  k_agg1<<<((size_t)N * 16 + TPB - 1) / TPB, TPB, 0, stream>>>(x, csr, noffs, We1, be1, u1, N);
  k_mlp9<<<(N + 63) / 64, TPB, 0, stream>>>(u1, W1a, b1a, W1b, b1b, h1h, N);

  k_agg2<<<((size_t)N * 64 + TPB - 1) / TPB, TPB, 0, stream>>>(h1h, (const long long*)csr, noffs, We2, be2, u2, N);
  k_mlp_ro<<<(N + 63) / 64, TPB, 0, stream>>>(u2, W2a, b2a, W2b, b2b, Wr1, br1, Wr2, br2, tmask, pi, N);

  k_grpsum<<<(N + TPB - 1) / TPB, TPB, 0, stream>>>(pi, ccost, batch, exp_t, N);
  k_final<<<(N + TPB - 1) / TPB, TPB, 0, stream>>>(pi, batch, Btot, exp_t, out, N);
}

// Round 9
// 454.439 us; speedup vs baseline: 1.2448x; 1.2448x over previous
//
#include <hip/hip_runtime.h>
#include <hip/hip_fp16.h>
#include <math.h>

#define TPB 256
#define P_BLOCKS 512
#define BSHIFT 8          // 256 nodes per bin
#define BINS_MAX 512      // >= ceil(100000/256)=391
#define PAD_ATTR 0x7fc00000  // quiet NaN: fmaxf(NaN+x,0)=0 -> pad edges contribute exactly 0

struct alignas(8)  h2x2 { __half2 a, b; };
struct alignas(16) h2x4 { __half2 a, b, c, d; };

typedef _Float16 f16;
typedef __attribute__((ext_vector_type(8))) _Float16 f16x8;
typedef __attribute__((ext_vector_type(4))) float f32x4;

#define MFMA16(a, b, c) __builtin_amdgcn_mfma_f32_16x16x32_f16(a, b, c, 0, 0, 0)

// ---------------- bucketed histogram: counts[bin*P + blk] ----------------
__global__ void __launch_bounds__(256) k_bhist(const int* __restrict__ dst,
                                               int* __restrict__ counts, int E, int B) {
  __shared__ int h[BINS_MAX];
  int t = threadIdx.x, blk = blockIdx.x;
  for (int i = t; i < B; i += TPB) h[i] = 0;
  __syncthreads();
  int chunk = (E + P_BLOCKS - 1) / P_BLOCKS;
  int s = blk * chunk, e = min(E, s + chunk);
  for (int i = s + t; i < e; i += TPB)
    atomicAdd(&h[__builtin_nontemporal_load(&dst[i]) >> BSHIFT], 1);
  __syncthreads();
  for (int i = t; i < B; i += TPB) counts[i * P_BLOCKS + blk] = h[i];
}

// ---------------- scan (1024 items/block) ----------------
__global__ void k_scan_block(const int* __restrict__ deg, int* __restrict__ offs,
                             int* __restrict__ bsums, int n) {
  __shared__ int lds[256];
  int t = threadIdx.x, b = blockIdx.x;
  int base = b * 1024 + t * 4;
  int v0 = (base + 0 < n) ? deg[base + 0] : 0;
  int v1 = (base + 1 < n) ? deg[base + 1] : 0;
  int v2 = (base + 2 < n) ? deg[base + 2] : 0;
  int v3 = (base + 3 < n) ? deg[base + 3] : 0;
  int s = v0 + v1 + v2 + v3;
  lds[t] = s;
  __syncthreads();
  int acc = s;
  for (int off = 1; off < 256; off <<= 1) {
    int x = (t >= off) ? lds[t - off] : 0;
    __syncthreads();
    acc += x;
    lds[t] = acc;
    __syncthreads();
  }
  int excl = acc - s;
  if (base + 0 < n) offs[base + 0] = excl;
  if (base + 1 < n) offs[base + 1] = excl + v0;
  if (base + 2 < n) offs[base + 2] = excl + v0 + v1;
  if (base + 3 < n) offs[base + 3] = excl + v0 + v1 + v2;
  if (t == 255) bsums[b] = acc;
}

// scan variant: element = pad32(deg) = (deg+31)&~31
__global__ void k_scan_block_pad(const int* __restrict__ deg, int* __restrict__ offs,
                                 int* __restrict__ bsums, int n) {
  __shared__ int lds[256];
  int t = threadIdx.x, b = blockIdx.x;
  int base = b * 1024 + t * 4;
  int v0 = (base + 0 < n) ? ((deg[base + 0] + 31) & ~31) : 0;
  int v1 = (base + 1 < n) ? ((deg[base + 1] + 31) & ~31) : 0;
  int v2 = (base + 2 < n) ? ((deg[base + 2] + 31) & ~31) : 0;
  int v3 = (base + 3 < n) ? ((deg[base + 3] + 31) & ~31) : 0;
  int s = v0 + v1 + v2 + v3;
  lds[t] = s;
  __syncthreads();
  int acc = s;
  for (int off = 1; off < 256; off <<= 1) {
    int x = (t >= off) ? lds[t - off] : 0;
    __syncthreads();
    acc += x;
    lds[t] = acc;
    __syncthreads();
  }
  int excl = acc - s;
  if (base + 0 < n) offs[base + 0] = excl;
  if (base + 1 < n) offs[base + 1] = excl + v0;
  if (base + 2 < n) offs[base + 2] = excl + v0 + v1;
  if (base + 3 < n) offs[base + 3] = excl + v0 + v1 + v2;
  if (t == 255) bsums[b] = acc;
}

__global__ void k_scan_mid(int* __restrict__ bsums, int nb) {
  __shared__ int lds[256];
  int t = threadIdx.x;
  int v = (t < nb) ? bsums[t] : 0;
  lds[t] = v;
  __syncthreads();
  int acc = v;
  for (int off = 1; off < 256; off <<= 1) {
    int x = (t >= off) ? lds[t - off] : 0;
    __syncthreads();
    acc += x;
    lds[t] = acc;
    __syncthreads();
  }
  if (t < nb) bsums[t] = acc - v;  // exclusive
}

__global__ void k_scan_add(int* __restrict__ offs, const int* __restrict__ bsums,
                           int n, int total) {
  int t = threadIdx.x, b = blockIdx.x;
  int add = bsums[b];
  int base = b * 1024 + t * 4;
#pragma unroll
  for (int j = 0; j < 4; ++j)
    if (base + j < n) offs[base + j] += add;
  if (b == 0 && t == 0) offs[n] = total;
}

// ---------------- fill: atomic-free (LDS cursors), streaming bin appends ----------------
__global__ void __launch_bounds__(256) k_bfill(const int* __restrict__ src,
                                               const int* __restrict__ dst,
                                               const float* __restrict__ attr,
                                               const int* __restrict__ offs,
                                               int2* __restrict__ ebuf, int E, int B) {
  __shared__ int cur[BINS_MAX];
  int t = threadIdx.x, blk = blockIdx.x;
  for (int i = t; i < B; i += TPB) cur[i] = offs[i * P_BLOCKS + blk];
  __syncthreads();
  int chunk = (E + P_BLOCKS - 1) / P_BLOCKS;
  int s = blk * chunk, e = min(E, s + chunk);
#pragma unroll 4
  for (int i = s + t; i < e; i += TPB) {
    int d = __builtin_nontemporal_load(&dst[i]);
    int sv = __builtin_nontemporal_load(&src[i]);
    float av = __builtin_nontemporal_load(&attr[i]);
    int bin = d >> BSHIFT;
    int pos = atomicAdd(&cur[bin], 1);
    ebuf[pos] = make_int2((sv << BSHIFT) | (d & ((1 << BSHIFT) - 1)), __float_as_int(av));
  }
}

// ---------------- bsort pass A: per-bucket histogram -> per-node degree ----------------
__global__ void __launch_bounds__(256) k_bsort_a(const long long* __restrict__ ebuf,
                                                 const int* __restrict__ offs,
                                                 int* __restrict__ pdeg, int N) {
  __shared__ int hist[256];
  int t = threadIdx.x, bkt = blockIdx.x;
  hist[t] = 0;
  __syncthreads();
  int s = offs[bkt * P_BLOCKS], e = offs[(bkt + 1) * P_BLOCKS];
#pragma unroll 4
  for (int i = s + t; i < e; i += TPB) {
    long long pv = __builtin_nontemporal_load(&ebuf[i]);
    atomicAdd(&hist[(int)(pv & 255)], 1);
  }
  __syncthreads();
  int n = (bkt << BSHIFT) + t;
  if (n < N) pdeg[n] = hist[t];
}

// ---------------- bsort pass B: scatter into PADDED csr + NaN pad-fill ----------------
__global__ void __launch_bounds__(256) k_bsort_b(const long long* __restrict__ ebuf,
                                                 const int* __restrict__ offs,
                                                 const int* __restrict__ noffs,
                                                 int2* __restrict__ csr, int N) {
  __shared__ int cursor[256];
  int t = threadIdx.x, bkt = blockIdx.x;
  int n = (bkt << BSHIFT) + t;
  cursor[t] = (n < N) ? noffs[n] : 0;
  __syncthreads();
  int s = offs[bkt * P_BLOCKS], e = offs[(bkt + 1) * P_BLOCKS];
#pragma unroll 4
  for (int i = s + t; i < e; i += TPB) {
    long long pv = __builtin_nontemporal_load(&ebuf[i]);
    int key = (int)(unsigned int)(pv & 0xffffffffLL);
    int attr = (int)(unsigned int)(((unsigned long long)pv) >> 32);
    int pos = atomicAdd(&cursor[key & 255], 1);
    csr[pos] = make_int2(((unsigned int)key) >> BSHIFT, attr);
  }
  __syncthreads();
  if (n < N) {
    int end = noffs[n + 1];
    for (int i = cursor[t]; i < end; ++i) csr[i] = make_int2(0, PAD_ATTR);
  }
}

// ---------------- Layer-1 aggregation: 16 threads/node, f<9 active ----------------
// Padded segments (multiple of 32) -> 8-edge passes with NO masks/clamps.
// Pad entries: attr=NaN -> fmaxf(NaN,0)=0, identical 0-contribution as old masked form.
__global__ void __launch_bounds__(256) k_agg1(
    const float* __restrict__ x, const int2* __restrict__ csr,
    const int* __restrict__ noffs, const float* __restrict__ We1,
    const float* __restrict__ be1, float* __restrict__ u1, int N) {
  int t = blockIdx.x * TPB + threadIdx.x;
  int node = t >> 4, f = t & 15;
  if (node >= N || f >= 9) return;
  int o0 = noffs[node], o1 = noffs[node + 1];
  float we = We1[f], be = be1[f];
  float acc = 0.f;
  for (int e = o0; e < o1; e += 8) {
    int2 p0 = csr[e],     p1 = csr[e + 1], p2 = csr[e + 2], p3 = csr[e + 3];
    int2 p4 = csr[e + 4], p5 = csr[e + 5], p6 = csr[e + 6], p7 = csr[e + 7];
    float v0 = x[p0.x * 9 + f] + fmaf(__int_as_float(p0.y), we, be);
    float v1 = x[p1.x * 9 + f] + fmaf(__int_as_float(p1.y), we, be);
    float v2 = x[p2.x * 9 + f] + fmaf(__int_as_float(p2.y), we, be);
    float v3 = x[p3.x * 9 + f] + fmaf(__int_as_float(p3.y), we, be);
    float v4 = x[p4.x * 9 + f] + fmaf(__int_as_float(p4.y), we, be);
    float v5 = x[p5.x * 9 + f] + fmaf(__int_as_float(p5.y), we, be);
    float v6 = x[p6.x * 9 + f] + fmaf(__int_as_float(p6.y), we, be);
    float v7 = x[p7.x * 9 + f] + fmaf(__int_as_float(p7.y), we, be);
    acc += fmaxf(v0, 0.f);
    acc += fmaxf(v1, 0.f);
    acc += fmaxf(v2, 0.f);
    acc += fmaxf(v3, 0.f);
    acc += fmaxf(v4, 0.f);
    acc += fmaxf(v5, 0.f);
    acc += fmaxf(v6, 0.f);
    acc += fmaxf(v7, 0.f);
  }
  u1[node * 9 + f] = x[node * 9 + f] + acc;
}

// ---------------- Layer-2 aggregation: one wave/node; 8 edge-slots x 8 feature-chunks ----------------
// Two-tier schedule (8-deep while >32 remain, 4-deep final 32), mask/clamp-FREE thanks
// to 32-padded segments. Scalar f32 math (R6: packed f32x2 -> VGPR cliff). VGPR < 64.
__global__ void __launch_bounds__(256) k_agg2(
    const __half* __restrict__ h1, const long long* __restrict__ csr,
    const int* __restrict__ noffs, const float* __restrict__ We2,
    const float* __restrict__ be2, float* __restrict__ u2, int N) {
  int gt = blockIdx.x * TPB + threadIdx.x;
  int node = gt >> 6;
  if (node >= N) return;
  int lane = gt & 63;
  int q = lane >> 3, c = lane & 7;
  float4 weA = *(const float4*)&We2[c * 8];
  float4 weB = *(const float4*)&We2[c * 8 + 4];
  float4 beA = *(const float4*)&be2[c * 8];
  float4 beB = *(const float4*)&be2[c * 8 + 4];
  int o0 = noffs[node], o1 = noffs[node + 1];
  float a0 = 0.f, a1 = 0.f, a2 = 0.f, a3 = 0.f, a4 = 0.f, a5 = 0.f, a6 = 0.f, a7 = 0.f;

#define AGG2_ACC(pv, v)                                                      \
  {                                                                          \
    float ea = __int_as_float((int)(unsigned int)(((unsigned long long)(pv)) >> 32)); \
    float2 f0 = __half22float2((v).a), f1 = __half22float2((v).b);           \
    float2 f2 = __half22float2((v).c), f3 = __half22float2((v).d);           \
    a0 += fmaxf(f0.x + fmaf(ea, weA.x, beA.x), 0.f);                         \
    a1 += fmaxf(f0.y + fmaf(ea, weA.y, beA.y), 0.f);                         \
    a2 += fmaxf(f1.x + fmaf(ea, weA.z, beA.z), 0.f);                         \
    a3 += fmaxf(f1.y + fmaf(ea, weA.w, beA.w), 0.f);                         \
    a4 += fmaxf(f2.x + fmaf(ea, weB.x, beB.x), 0.f);                         \
    a5 += fmaxf(f2.y + fmaf(ea, weB.y, beB.y), 0.f);                         \
    a6 += fmaxf(f3.x + fmaf(ea, weB.z, beB.z), 0.f);                         \
    a7 += fmaxf(f3.y + fmaf(ea, weB.w, beB.w), 0.f);                         \
  }

  int e = o0;
  // 8-deep passes while remaining > 32 (remaining is a multiple of 32 -> >=64)
  if (o1 - e > 32) {
    do {
      long long pv0 = __builtin_nontemporal_load(&csr[e + q]);
      long long pv1 = __builtin_nontemporal_load(&csr[e + 8 + q]);
      long long pv2 = __builtin_nontemporal_load(&csr[e + 16 + q]);
      long long pv3 = __builtin_nontemporal_load(&csr[e + 24 + q]);
      long long pv4 = __builtin_nontemporal_load(&csr[e + 32 + q]);
      long long pv5 = __builtin_nontemporal_load(&csr[e + 40 + q]);
      long long pv6 = __builtin_nontemporal_load(&csr[e + 48 + q]);
      long long pv7 = __builtin_nontemporal_load(&csr[e + 56 + q]);
      h2x4 v0 = *(const h2x4*)(h1 + (size_t)(int)(unsigned int)(pv0 & 0xffffffffLL) * 64 + c * 8);
      h2x4 v1 = *(const h2x4*)(h1 + (size_t)(int)(unsigned int)(pv1 & 0xffffffffLL) * 64 + c * 8);
      h2x4 v2 = *(const h2x4*)(h1 + (size_t)(int)(unsigned int)(pv2 & 0xffffffffLL) * 64 + c * 8);
      h2x4 v3 = *(const h2x4*)(h1 + (size_t)(int)(unsigned int)(pv3 & 0xffffffffLL) * 64 + c * 8);
      h2x4 v4 = *(const h2x4*)(h1 + (size_t)(int)(unsigned int)(pv4 & 0xffffffffLL) * 64 + c * 8);
      h2x4 v5 = *(const h2x4*)(h1 + (size_t)(int)(unsigned int)(pv5 & 0xffffffffLL) * 64 + c * 8);
      h2x4 v6 = *(const h2x4*)(h1 + (size_t)(int)(unsigned int)(pv6 & 0xffffffffLL) * 64 + c * 8);
      h2x4 v7 = *(const h2x4*)(h1 + (size_t)(int)(unsigned int)(pv7 & 0xffffffffLL) * 64 + c * 8);
      AGG2_ACC(pv0, v0); AGG2_ACC(pv1, v1);
      AGG2_ACC(pv2, v2); AGG2_ACC(pv3, v3);
      AGG2_ACC(pv4, v4); AGG2_ACC(pv5, v5);
      AGG2_ACC(pv6, v6); AGG2_ACC(pv7, v7);
      e += 64;
    } while (o1 - e > 32);
  }
  // final tier: exactly 32 edges (or 0), 4-deep, no masks
  if (e < o1) {
    long long pv0 = __builtin_nontemporal_load(&csr[e + q]);
    long long pv1 = __builtin_nontemporal_load(&csr[e + 8 + q]);
    long long pv2 = __builtin_nontemporal_load(&csr[e + 16 + q]);
    long long pv3 = __builtin_nontemporal_load(&csr[e + 24 + q]);
    h2x4 v0 = *(const h2x4*)(h1 + (size_t)(int)(unsigned int)(pv0 & 0xffffffffLL) * 64 + c * 8);
    h2x4 v1 = *(const h2x4*)(h1 + (size_t)(int)(unsigned int)(pv1 & 0xffffffffLL) * 64 + c * 8);
    h2x4 v2 = *(const h2x4*)(h1 + (size_t)(int)(unsigned int)(pv2 & 0xffffffffLL) * 64 + c * 8);
    h2x4 v3 = *(const h2x4*)(h1 + (size_t)(int)(unsigned int)(pv3 & 0xffffffffLL) * 64 + c * 8);
    AGG2_ACC(pv0, v0); AGG2_ACC(pv1, v1);
    AGG2_ACC(pv2, v2); AGG2_ACC(pv3, v3);
  }
#undef AGG2_ACC

  a0 += __shfl_xor(a0, 8, 64); a0 += __shfl_xor(a0, 16, 64); a0 += __shfl_xor(a0, 32, 64);
  a1 += __shfl_xor(a1, 8, 64); a1 += __shfl_xor(a1, 16, 64); a1 += __shfl_xor(a1, 32, 64);
  a2 += __shfl_xor(a2, 8, 64); a2 += __shfl_xor(a2, 16, 64); a2 += __shfl_xor(a2, 32, 64);
  a3 += __shfl_xor(a3, 8, 64); a3 += __shfl_xor(a3, 16, 64); a3 += __shfl_xor(a3, 32, 64);
  a4 += __shfl_xor(a4, 8, 64); a4 += __shfl_xor(a4, 16, 64); a4 += __shfl_xor(a4, 32, 64);
  a5 += __shfl_xor(a5, 8, 64); a5 += __shfl_xor(a5, 16, 64); a5 += __shfl_xor(a5, 32, 64);
  a6 += __shfl_xor(a6, 8, 64); a6 += __shfl_xor(a6, 16, 64); a6 += __shfl_xor(a6, 32, 64);
  a7 += __shfl_xor(a7, 8, 64); a7 += __shfl_xor(a7, 16, 64); a7 += __shfl_xor(a7, 32, 64);

  if (q == 0) {
    h2x4 sf = *(const h2x4*)(h1 + (size_t)node * 64 + c * 8);
    float2 s0 = __half22float2(sf.a), s1 = __half22float2(sf.b);
    float2 s2 = __half22float2(sf.c), s3 = __half22float2(sf.d);
    float4 oA, oB;
    oA.x = s0.x + a0; oA.y = s0.y + a1; oA.z = s1.x + a2; oA.w = s1.y + a3;
    oB.x = s2.x + a4; oB.y = s2.y + a5; oB.z = s3.x + a6; oB.w = s3.y + a7;
    *(float4*)&u2[(size_t)node * 64 + c * 8] = oA;
    *(float4*)&u2[(size_t)node * 64 + c * 8 + 4] = oB;
  }
}

// ---------------- split-fp16 helpers for MFMA (f32-class accuracy) ----------------
__device__ __forceinline__ void splitf8(const float* v, f16x8& h, f16x8& l) {
#pragma unroll
  for (int j = 0; j < 8; ++j) {
    float x = v[j];
    f16 hh = (f16)x;
    h[j] = hh;
    l[j] = (f16)(x - (float)hh);
  }
}

// pack W [K][Nout] row-major into per-lane MFMA B-fragments (hi/lo planes).
__device__ __forceinline__ void pack_w(const float* __restrict__ W, int Ntiles, int nslots,
                                       f16* hi, f16* lo, int t) {
  int lane = t & 63;
  int kg = lane >> 4, m = lane & 15;
  int Nout = Ntiles * 16;
  for (int s = t >> 6; s < nslots; s += 4) {
    int ks = s / Ntiles, nt = s - ks * Ntiles;
    int kbase = ks * 32 + kg * 8;
    int n = nt * 16 + m;
    float v[8];
#pragma unroll
    for (int j = 0; j < 8; ++j) v[j] = W[(kbase + j) * Nout + n];
    f16x8 h, l;
    splitf8(v, h, l);
    *(f16x8*)&hi[(s * 64 + lane) * 8] = h;
    *(f16x8*)&lo[(s * 64 + lane) * 8] = l;
  }
}

// ---------------- Layer-1 MLP (9->64->64) via split-fp16 MFMA, fp16 output ----------------
__global__ void __launch_bounds__(256) k_mlp9(
    const float* __restrict__ uin, const float* __restrict__ Wa,
    const float* __restrict__ ba, const float* __restrict__ Wb,
    const float* __restrict__ bb, __half* __restrict__ hout, int N) {
  __shared__ __align__(16) f16 wf1h[2048], wf1l[2048];
  __shared__ __align__(16) f16 wf2h[4096], wf2l[4096];
  __shared__ float ls_z[64 * 65];
  __shared__ float ls_ba[64], ls_bb[64];
  const int t = threadIdx.x;
  const int n0 = blockIdx.x * 64;
  const int w = t >> 6, lane = t & 63;
  const int m = lane & 15, kg = lane >> 4;

  {
    int s = w;
    int n = s * 16 + m;
    float v[8];
#pragma unroll
    for (int j = 0; j < 8; ++j) {
      int k = kg * 8 + j;
      v[j] = (k < 9) ? Wa[k * 64 + n] : 0.f;
    }
    f16x8 h, l;
    splitf8(v, h, l);
    *(f16x8*)&wf1h[(s * 64 + lane) * 8] = h;
    *(f16x8*)&wf1l[(s * 64 + lane) * 8] = l;
  }
  pack_w(Wb, 4, 8, wf2h, wf2l, t);
  if (t < 64) { ls_ba[t] = ba[t]; ls_bb[t] = bb[t]; }
  __syncthreads();

  int row = min(n0 + w * 16 + m, N - 1);
  float av[8];
#pragma unroll
  for (int j = 0; j < 8; ++j) {
    int k = kg * 8 + j;
    av[j] = (k < 9) ? uin[(size_t)row * 9 + k] : 0.f;
  }
  f16x8 a0h, a0l, a1h, a1l;
  splitf8(av, a0h, a0l);

  f32x4 acc[4];
#pragma unroll
  for (int nt = 0; nt < 4; ++nt) { f32x4 z4 = {0.f, 0.f, 0.f, 0.f}; acc[nt] = z4; }
#pragma unroll
  for (int nt = 0; nt < 4; ++nt) {
    f16x8 bh = *(const f16x8*)&wf1h[(nt * 64 + lane) * 8];
    f16x8 bl = *(const f16x8*)&wf1l[(nt * 64 + lane) * 8];
    acc[nt] = MFMA16(a0h, bh, acc[nt]);
    acc[nt] = MFMA16(a0l, bh, acc[nt]);
    acc[nt] = MFMA16(a0h, bl, acc[nt]);
  }
#pragma unroll
  for (int nt = 0; nt < 4; ++nt)
#pragma unroll
    for (int r = 0; r < 4; ++r)
      ls_z[(w * 16 + kg * 4 + r) * 65 + nt * 16 + m] = fmaxf(acc[nt][r] + ls_ba[nt * 16 + m], 0.f);
  __syncthreads();

  const float* zr = &ls_z[(size_t)(w * 16 + m) * 65 + kg * 8];
  {
    float zv0[8], zv1[8];
#pragma unroll
    for (int j = 0; j < 8; ++j) { zv0[j] = zr[j]; zv1[j] = zr[32 + j]; }
    splitf8(zv0, a0h, a0l);
    splitf8(zv1, a1h, a1l);
  }
#pragma unroll
  for (int nt = 0; nt < 4; ++nt) { f32x4 z4 = {0.f, 0.f, 0.f, 0.f}; acc[nt] = z4; }
#pragma unroll
  for (int nt = 0; nt < 4; ++nt) {
#pragma unroll
    for (int ks = 0; ks < 2; ++ks) {
      int s = ks * 4 + nt;
      f16x8 bh = *(const f16x8*)&wf2h[(s * 64 + lane) * 8];
      f16x8 bl = *(const f16x8*)&wf2l[(s * 64 + lane) * 8];
      f16x8 ah = ks ? a1h : a0h;
      f16x8 al = ks ? a1l : a0l;
      acc[nt] = MFMA16(ah, bh, acc[nt]);
      acc[nt] = MFMA16(al, bh, acc[nt]);
      acc[nt] = MFMA16(ah, bl, acc[nt]);
    }
  }
#pragma unroll
  for (int nt = 0; nt < 4; ++nt)
#pragma unroll
    for (int r = 0; r < 4; ++r) {
      int node = n0 + w * 16 + kg * 4 + r;
      if (node < N)
        hout[(size_t)node * 64 + nt * 16 + m] =
            __float2half(fmaxf(acc[nt][r] + ls_bb[nt * 16 + m], 0.f));
    }
}

// ---------------- Layer-2 MLP (64->64->64) + readout via split-fp16 MFMA ----------------
__global__ void __launch_bounds__(256) k_mlp_ro(
    const float* __restrict__ uin, const float* __restrict__ Wa,
    const float* __restrict__ ba, const float* __restrict__ Wb,
    const float* __restrict__ bb, const float* __restrict__ Wr1,
    const float* __restrict__ br1, const float* __restrict__ Wr2,
    const float* __restrict__ br2, const int* __restrict__ tmask,
    float* __restrict__ pi, int N) {
  __shared__ __align__(16) f16 wf1h[4096], wf1l[4096];
  __shared__ __align__(16) f16 wf2h[4096], wf2l[4096];
  __shared__ __align__(16) f16 wfrh[2048], wfrl[2048];
  __shared__ float ls_z[64 * 65];
  __shared__ float ls_ba[64], ls_bb[64], ls_br1[32], ls_w2[32];
  const int t = threadIdx.x;
  const int n0 = blockIdx.x * 64;

  pack_w(Wa, 4, 8, wf1h, wf1l, t);
  pack_w(Wb, 4, 8, wf2h, wf2l, t);
  pack_w(Wr1, 2, 4, wfrh, wfrl, t);
  if (t < 64) { ls_ba[t] = ba[t]; ls_bb[t] = bb[t]; }
  else if (t < 96) { ls_br1[t - 64] = br1[t - 64]; ls_w2[t - 64] = Wr2[t - 64]; }
  __syncthreads();

  const int w = t >> 6, lane = t & 63;
  const int m = lane & 15, kg = lane >> 4;

  int row = n0 + w * 16 + m;
  row = min(row, N - 1);
  const float* ar = uin + (size_t)row * 64 + kg * 8;
  float av0[8], av1[8];
  {
    f32x4 p0 = *(const f32x4*)ar;
    f32x4 p1 = *(const f32x4*)(ar + 4);
    f32x4 p2 = *(const f32x4*)(ar + 32);
    f32x4 p3 = *(const f32x4*)(ar + 36);
#pragma unroll
    for (int j = 0; j < 4; ++j) {
      av0[j] = p0[j]; av0[4 + j] = p1[j];
      av1[j] = p2[j]; av1[4 + j] = p3[j];
    }
  }
  f16x8 a0h, a0l, a1h, a1l;
  splitf8(av0, a0h, a0l);
  splitf8(av1, a1h, a1l);

  f32x4 acc[4];
#pragma unroll
  for (int nt = 0; nt < 4; ++nt) { f32x4 z4 = {0.f, 0.f, 0.f, 0.f}; acc[nt] = z4; }
#pragma unroll
  for (int nt = 0; nt < 4; ++nt) {
#pragma unroll
    for (int ks = 0; ks < 2; ++ks) {
      int s = ks * 4 + nt;
      f16x8 bh = *(const f16x8*)&wf1h[(s * 64 + lane) * 8];
      f16x8 bl = *(const f16x8*)&wf1l[(s * 64 + lane) * 8];
      f16x8 ah = ks ? a1h : a0h;
      f16x8 al = ks ? a1l : a0l;
      acc[nt] = MFMA16(ah, bh, acc[nt]);
      acc[nt] = MFMA16(al, bh, acc[nt]);
      acc[nt] = MFMA16(ah, bl, acc[nt]);
    }
  }
#pragma unroll
  for (int nt = 0; nt < 4; ++nt)
#pragma unroll
    for (int r = 0; r < 4; ++r)
      ls_z[(w * 16 + kg * 4 + r) * 65 + nt * 16 + m] = fmaxf(acc[nt][r] + ls_ba[nt * 16 + m], 0.f);
  __syncthreads();

  const float* zr = &ls_z[(size_t)(w * 16 + m) * 65 + kg * 8];
  {
    float zv0[8], zv1[8];
#pragma unroll
    for (int j = 0; j < 8; ++j) { zv0[j] = zr[j]; zv1[j] = zr[32 + j]; }
    splitf8(zv0, a0h, a0l);
    splitf8(zv1, a1h, a1l);
  }
#pragma unroll
  for (int nt = 0; nt < 4; ++nt) { f32x4 z4 = {0.f, 0.f, 0.f, 0.f}; acc[nt] = z4; }
#pragma unroll
  for (int nt = 0; nt < 4; ++nt) {
#pragma unroll
    for (int ks = 0; ks < 2; ++ks) {
      int s = ks * 4 + nt;
      f16x8 bh = *(const f16x8*)&wf2h[(s * 64 + lane) * 8];
      f16x8 bl = *(const f16x8*)&wf2l[(s * 64 + lane) * 8];
      f16x8 ah = ks ? a1h : a0h;
      f16x8 al = ks ? a1l : a0l;
      acc[nt] = MFMA16(ah, bh, acc[nt]);
      acc[nt] = MFMA16(al, bh, acc[nt]);
      acc[nt] = MFMA16(ah, bl, acc[nt]);
    }
  }
  __syncthreads();
#pragma unroll
  for (int nt = 0; nt < 4; ++nt)
#pragma unroll
    for (int r = 0; r < 4; ++r)
      ls_z[(w * 16 + kg * 4 + r) * 65 + nt * 16 + m] = fmaxf(acc[nt][r] + ls_bb[nt * 16 + m], 0.f);
  __syncthreads();

  {
    float zv0[8], zv1[8];
#pragma unroll
    for (int j = 0; j < 8; ++j) { zv0[j] = zr[j]; zv1[j] = zr[32 + j]; }
    splitf8(zv0, a0h, a0l);
    splitf8(zv1, a1h, a1l);
  }
  f32x4 accr[2];
#pragma unroll
  for (int nt = 0; nt < 2; ++nt) { f32x4 z4 = {0.f, 0.f, 0.f, 0.f}; accr[nt] = z4; }
#pragma unroll
  for (int nt = 0; nt < 2; ++nt) {
#pragma unroll
    for (int ks = 0; ks < 2; ++ks) {
      int s = ks * 2 + nt;
      f16x8 bh = *(const f16x8*)&wfrh[(s * 64 + lane) * 8];
      f16x8 bl = *(const f16x8*)&wfrl[(s * 64 + lane) * 8];
      f16x8 ah = ks ? a1h : a0h;
      f16x8 al = ks ? a1l : a0l;
      accr[nt] = MFMA16(ah, bh, accr[nt]);
      accr[nt] = MFMA16(al, bh, accr[nt]);
      accr[nt] = MFMA16(ah, bl, accr[nt]);
    }
  }
  float b2 = br2[0];
#pragma unroll
  for (int r = 0; r < 4; ++r) {
    float v0 = fmaxf(accr[0][r] + ls_br1[m], 0.f) * ls_w2[m];
    float v1 = fmaxf(accr[1][r] + ls_br1[16 + m], 0.f) * ls_w2[16 + m];
    float tr = v0 + v1;
    tr += __shfl_xor(tr, 1, 64);
    tr += __shfl_xor(tr, 2, 64);
    tr += __shfl_xor(tr, 4, 64);
    tr += __shfl_xor(tr, 8, 64);
    if (m == 0) {
      int node = n0 + w * 16 + kg * 4 + r;
      if (node < N) {
        float sg = 1.f / (1.f + expf(-(tr + b2)));
        pi[node] = sg * (1.f - (float)tmask[node]);
      }
    }
  }
}

// ---------------- Group sums (batch sorted) ----------------
__global__ void k_grpsum(const float* __restrict__ pi, const float* __restrict__ c_cost,
                         const int* __restrict__ batch, float* __restrict__ exp_tot, int N) {
  __shared__ float lsf[256];
  __shared__ int lsi[256];
  int t = threadIdx.x;
  int i = blockIdx.x * TPB + t;
  bool valid = i < N;
  int g = valid ? batch[i] : 0;
  float v = valid ? pi[i] * c_cost[i] : 0.f;
  lsi[t] = valid ? g : 0x7fffffff;
  __syncthreads();
  for (int s = 128; s > 0; s >>= 1) { if (t < s) lsi[t] = min(lsi[t], lsi[t + s]); __syncthreads(); }
  int gmin = lsi[0];
  __syncthreads();
  lsi[t] = valid ? g : -1;
  __syncthreads();
  for (int s = 128; s > 0; s >>= 1) { if (t < s) lsi[t] = max(lsi[t], lsi[t + s]); __syncthreads(); }
  int gmax = lsi[0];
  __syncthreads();
  for (int gg = gmin; gg <= gmax; ++gg) {
    lsf[t] = (valid && g == gg) ? v : 0.f;
    __syncthreads();
    for (int s = 128; s > 0; s >>= 1) { if (t < s) lsf[t] += lsf[t + s]; __syncthreads(); }
    if (t == 0) atomicAdd(&exp_tot[gg], lsf[0]);
    __syncthreads();
  }
}

__global__ void k_final(const float* __restrict__ pi, const int* __restrict__ batch,
                        const float* __restrict__ B_total, const float* __restrict__ exp_tot,
                        float* __restrict__ out, int N) {
  int i = blockIdx.x * TPB + threadIdx.x;
  if (i < N) {
    int g = batch[i];
    float ratio = fminf(B_total[g] / (exp_tot[g] + 1e-12f), 1.f);
    out[i] = pi[i] * ratio;
  }
}

extern "C" void kernel_launch(void* const* d_in, const int* in_sizes, int n_in,
                              void* d_out, int out_size, void* d_ws, size_t ws_size,
                              hipStream_t stream) {
  const float* x     = (const float*)d_in[0];
  const int*   ei    = (const int*)d_in[1];
  const float* eattr = (const float*)d_in[2];
  const int*   batch = (const int*)d_in[3];
  const float* Btot  = (const float*)d_in[4];
  const int*   tmask = (const int*)d_in[5];
  const float* ccost = (const float*)d_in[6];
  const float* We1 = (const float*)d_in[7],  *be1 = (const float*)d_in[8];
  const float* W1a = (const float*)d_in[9],  *b1a = (const float*)d_in[10];
  const float* W1b = (const float*)d_in[11], *b1b = (const float*)d_in[12];
  const float* We2 = (const float*)d_in[13], *be2 = (const float*)d_in[14];
  const float* W2a = (const float*)d_in[15], *b2a = (const float*)d_in[16];
  const float* W2b = (const float*)d_in[17], *b2b = (const float*)d_in[18];
  const float* Wr1 = (const float*)d_in[19], *br1 = (const float*)d_in[20];
  const float* Wr2 = (const float*)d_in[21], *br2 = (const float*)d_in[22];
  float* out = (float*)d_out;

  const int N = in_sizes[0] / 9;
  const int E = in_sizes[2];
  const int G = in_sizes[4];
  const int* src = ei;
  const int* dst = ei + E;
  const int B = (N + (1 << BSHIFT) - 1) >> BSHIFT;  // 256-node bins
  const int nscan = B * P_BLOCKS;

  // workspace carve-up (4-byte elements)
  size_t cur = 0;
  auto alloc = [&](size_t elems) { size_t r = cur; cur += elems; cur = (cur + 63) & ~(size_t)63; return r; };
  char* wsb = (char*)d_ws;
  size_t o_exp    = alloc(G);                 // zeroed
  size_t o_counts = alloc(nscan);
  size_t o_offs   = alloc(nscan + 1);
  size_t o_bsums  = alloc(256);
  size_t o_pdeg   = alloc(N + 1);             // per-node degree (zeroed; [N]=0 for scan)
  size_t o_noffs  = alloc(N + 2);             // padded offsets
  size_t csr_cap  = (size_t)E + 31 * (size_t)N + 64;  // worst-case pad32
  size_t o_csr    = alloc(2 * csr_cap);
  // ebuf region (2E ints, dead after bsort_b) hosts h1 (N*32) + u1 (N*9) + pi (N)
  size_t need_hup = (size_t)N * 32 + (size_t)N * 9 + (size_t)N + 64;
  size_t e_or_h   = (2 * (size_t)E > need_hup) ? 2 * (size_t)E : need_hup;
  size_t o_ebuf   = alloc(e_or_h);
  size_t o_u2     = alloc((size_t)N * 64);
  (void)ws_size;

  float* exp_t  = (float*)wsb + o_exp;
  int*   counts = (int*)wsb + o_counts;
  int*   offs   = (int*)wsb + o_offs;
  int*   bsums  = (int*)wsb + o_bsums;
  int*   pdeg   = (int*)wsb + o_pdeg;
  int*   noffs  = (int*)wsb + o_noffs;
  int2*  csr    = (int2*)((int*)wsb + o_csr);
  int2*  ebuf   = (int2*)((int*)wsb + o_ebuf);
  __half* h1h   = (__half*)((int*)wsb + o_ebuf);                       // alias (post-bsort)
  float* u1     = (float*)((int*)wsb + o_ebuf + (size_t)N * 32);       // alias (post-bsort)
  float* pi     = (float*)((int*)wsb + o_ebuf + (size_t)N * 41);      // alias (post-bsort)
  float* u2     = (float*)wsb + o_u2;

  (void)hipMemsetAsync(exp_t, 0, (size_t)G * 4, stream);
  (void)hipMemsetAsync(pdeg, 0, ((size_t)N + 1) * 4, stream);

  const int nb1 = (nscan + 1023) / 1024;
  const int nb2 = (N + 1 + 1023) / 1024;

  k_bhist<<<P_BLOCKS, TPB, 0, stream>>>(dst, counts, E, B);
  k_scan_block<<<nb1, TPB, 0, stream>>>(counts, offs, bsums, nscan);
  k_scan_mid<<<1, 256, 0, stream>>>(bsums, nb1);
  k_scan_add<<<nb1, TPB, 0, stream>>>(offs, bsums, nscan, E);
  k_bfill<<<P_BLOCKS, TPB, 0, stream>>>(src, dst, eattr, offs, ebuf, E, B);

  k_bsort_a<<<B, TPB, 0, stream>>>((const long long*)ebuf, offs, pdeg, N);
  k_scan_block_pad<<<nb2, TPB, 0, stream>>>(pdeg, noffs, bsums, N + 1);
  k_scan_mid<<<1, 256, 0, stream>>>(bsums, nb2);
  k_scan_add<<<nb2, TPB, 0, stream>>>(noffs, bsums, N + 1, 0);
  k_bsort_b<<<B, TPB, 0, stream>>>((const long long*)ebuf, offs, noffs, csr, N);

  k_agg1<<<((size_t)N * 16 + TPB - 1) / TPB, TPB, 0, stream>>>(x, csr, noffs, We1, be1, u1, N);
  k_mlp9<<<(N + 63) / 64, TPB, 0, stream>>>(u1, W1a, b1a, W1b, b1b, h1h, N);

  k_agg2<<<((size_t)N * 64 + TPB - 1) / TPB, TPB, 0, stream>>>(h1h, (const long long*)csr, noffs, We2, be2, u2, N);
  k_mlp_ro<<<(N + 63) / 64, TPB, 0, stream>>>(u2, W2a, b2a, W2b, b2b, Wr1, br1, Wr2, br2, tmask, pi, N);

  k_grpsum<<<(N + TPB - 1) / TPB, TPB, 0, stream>>>(pi, ccost, batch, exp_t, N);
  k_final<<<(N + TPB - 1) / TPB, TPB, 0, stream>>>(pi, batch, Btot, exp_t, out, N);
}

// Round 10
// 413.540 us; speedup vs baseline: 1.3679x; 1.0989x over previous
//
#include <hip/hip_runtime.h>
#include <hip/hip_fp16.h>
#include <math.h>

#define TPB 256
#define P_BLOCKS 512
#define BSHIFT 8          // 256 nodes per bin
#define BINS_MAX 512      // >= ceil(100000/256)=391

struct alignas(8)  h2x2 { __half2 a, b; };
struct alignas(16) h2x4 { __half2 a, b, c, d; };

typedef _Float16 f16;
typedef __attribute__((ext_vector_type(8))) _Float16 f16x8;
typedef __attribute__((ext_vector_type(4))) float f32x4;

#define MFMA16(a, b, c) __builtin_amdgcn_mfma_f32_16x16x32_f16(a, b, c, 0, 0, 0)

// ---------------- bucketed histogram: counts[bin*P + blk] ----------------
__global__ void __launch_bounds__(256) k_bhist(const int* __restrict__ dst,
                                               int* __restrict__ counts, int E, int B) {
  __shared__ int h[BINS_MAX];
  int t = threadIdx.x, blk = blockIdx.x;
  for (int i = t; i < B; i += TPB) h[i] = 0;
  __syncthreads();
  int chunk = (E + P_BLOCKS - 1) / P_BLOCKS;
  int s = blk * chunk, e = min(E, s + chunk);
  for (int i = s + t; i < e; i += TPB)
    atomicAdd(&h[__builtin_nontemporal_load(&dst[i]) >> BSHIFT], 1);
  __syncthreads();
  for (int i = t; i < B; i += TPB) counts[i * P_BLOCKS + blk] = h[i];
}

// ---------------- scan (1024 items/block) ----------------
__global__ void k_scan_block(const int* __restrict__ deg, int* __restrict__ offs,
                             int* __restrict__ bsums, int n) {
  __shared__ int lds[256];
  int t = threadIdx.x, b = blockIdx.x;
  int base = b * 1024 + t * 4;
  int v0 = (base + 0 < n) ? deg[base + 0] : 0;
  int v1 = (base + 1 < n) ? deg[base + 1] : 0;
  int v2 = (base + 2 < n) ? deg[base + 2] : 0;
  int v3 = (base + 3 < n) ? deg[base + 3] : 0;
  int s = v0 + v1 + v2 + v3;
  lds[t] = s;
  __syncthreads();
  int acc = s;
  for (int off = 1; off < 256; off <<= 1) {
    int x = (t >= off) ? lds[t - off] : 0;
    __syncthreads();
    acc += x;
    lds[t] = acc;
    __syncthreads();
  }
  int excl = acc - s;
  if (base + 0 < n) offs[base + 0] = excl;
  if (base + 1 < n) offs[base + 1] = excl + v0;
  if (base + 2 < n) offs[base + 2] = excl + v0 + v1;
  if (base + 3 < n) offs[base + 3] = excl + v0 + v1 + v2;
  if (t == 255) bsums[b] = acc;
}

__global__ void k_scan_mid(int* __restrict__ bsums, int nb) {
  __shared__ int lds[256];
  int t = threadIdx.x;
  int v = (t < nb) ? bsums[t] : 0;
  lds[t] = v;
  __syncthreads();
  int acc = v;
  for (int off = 1; off < 256; off <<= 1) {
    int x = (t >= off) ? lds[t - off] : 0;
    __syncthreads();
    acc += x;
    lds[t] = acc;
    __syncthreads();
  }
  if (t < nb) bsums[t] = acc - v;  // exclusive
}

__global__ void k_scan_add(int* __restrict__ offs, const int* __restrict__ bsums,
                           int n, int total) {
  int t = threadIdx.x, b = blockIdx.x;
  int add = bsums[b];
  int base = b * 1024 + t * 4;
#pragma unroll
  for (int j = 0; j < 4; ++j)
    if (base + j < n) offs[base + j] += add;
  if (b == 0 && t == 0) offs[n] = total;
}

// ---------------- fill: atomic-free (LDS cursors), streaming bin appends ----------------
__global__ void __launch_bounds__(256) k_bfill(const int* __restrict__ src,
                                               const int* __restrict__ dst,
                                               const float* __restrict__ attr,
                                               const int* __restrict__ offs,
                                               int2* __restrict__ ebuf, int E, int B) {
  __shared__ int cur[BINS_MAX];
  int t = threadIdx.x, blk = blockIdx.x;
  for (int i = t; i < B; i += TPB) cur[i] = offs[i * P_BLOCKS + blk];
  __syncthreads();
  int chunk = (E + P_BLOCKS - 1) / P_BLOCKS;
  int s = blk * chunk, e = min(E, s + chunk);
#pragma unroll 4
  for (int i = s + t; i < e; i += TPB) {
    int d = __builtin_nontemporal_load(&dst[i]);
    int sv = __builtin_nontemporal_load(&src[i]);
    float av = __builtin_nontemporal_load(&attr[i]);
    int bin = d >> BSHIFT;
    int pos = atomicAdd(&cur[bin], 1);
    ebuf[pos] = make_int2((sv << BSHIFT) | (d & ((1 << BSHIFT) - 1)), __float_as_int(av));
  }
}

// ---------------- per-bin counting sort -> dst-sorted csr + node offsets ----------------
__global__ void __launch_bounds__(256) k_bsort(const long long* __restrict__ ebuf,
                                               const int* __restrict__ offs,
                                               int2* __restrict__ csr,
                                               int* __restrict__ noffs,
                                               int N, int E) {
  __shared__ int hist[256];
  __shared__ int cursor[256];
  __shared__ int sc[256];
  int t = threadIdx.x, bkt = blockIdx.x;
  hist[t] = 0;
  __syncthreads();
  int s = offs[bkt * P_BLOCKS], e = offs[(bkt + 1) * P_BLOCKS];
#pragma unroll 4
  for (int i = s + t; i < e; i += TPB) {
    long long pv = __builtin_nontemporal_load(&ebuf[i]);
    int key = (int)(unsigned int)(pv & 0xffffffffLL);
    atomicAdd(&hist[key & 255], 1);
  }
  __syncthreads();
  int v = hist[t];
  int acc = v;
  sc[t] = v;
  __syncthreads();
  for (int off = 1; off < 256; off <<= 1) {
    int x = (t >= off) ? sc[t - off] : 0;
    __syncthreads();
    acc += x;
    sc[t] = acc;
    __syncthreads();
  }
  int base = s + acc - v;  // exclusive within bucket
  cursor[t] = base;
  int n = (bkt << BSHIFT) + t;
  if (n < N) noffs[n] = base;
  if (bkt == 0 && t == 0) noffs[N] = E;
  __syncthreads();
#pragma unroll 4
  for (int i = s + t; i < e; i += TPB) {
    long long pv = __builtin_nontemporal_load(&ebuf[i]);
    int key = (int)(unsigned int)(pv & 0xffffffffLL);
    int attr = (int)(unsigned int)(((unsigned long long)pv) >> 32);
    int pos = atomicAdd(&cursor[key & 255], 1);
    csr[pos] = make_int2(((unsigned int)key) >> BSHIFT, attr);
  }
}

// ---------------- Layer-1 aggregation: 16 threads/node, f<9 active ----------------
// Predicated 8-edge passes (8 csr + 8 x-gathers in flight).
__global__ void __launch_bounds__(256) k_agg1(
    const float* __restrict__ x, const int2* __restrict__ csr,
    const int* __restrict__ noffs, const float* __restrict__ We1,
    const float* __restrict__ be1, float* __restrict__ u1, int N) {
  int t = blockIdx.x * TPB + threadIdx.x;
  int node = t >> 4, f = t & 15;
  if (node >= N || f >= 9) return;
  int o0 = noffs[node], o1 = noffs[node + 1];
  float we = We1[f], be = be1[f];
  float acc = 0.f;
  int last = o1 - 1;
  for (int e = o0; e < o1; e += 8) {
    int i0 = e;     bool m0 = i0 < o1; i0 = m0 ? i0 : last;
    int i1 = e + 1; bool m1 = i1 < o1; i1 = m1 ? i1 : last;
    int i2 = e + 2; bool m2 = i2 < o1; i2 = m2 ? i2 : last;
    int i3 = e + 3; bool m3 = i3 < o1; i3 = m3 ? i3 : last;
    int i4 = e + 4; bool m4 = i4 < o1; i4 = m4 ? i4 : last;
    int i5 = e + 5; bool m5 = i5 < o1; i5 = m5 ? i5 : last;
    int i6 = e + 6; bool m6 = i6 < o1; i6 = m6 ? i6 : last;
    int i7 = e + 7; bool m7 = i7 < o1; i7 = m7 ? i7 : last;
    int2 p0 = csr[i0], p1 = csr[i1], p2 = csr[i2], p3 = csr[i3];
    int2 p4 = csr[i4], p5 = csr[i5], p6 = csr[i6], p7 = csr[i7];
    float v0 = x[p0.x * 9 + f] + fmaf(__int_as_float(p0.y), we, be);
    float v1 = x[p1.x * 9 + f] + fmaf(__int_as_float(p1.y), we, be);
    float v2 = x[p2.x * 9 + f] + fmaf(__int_as_float(p2.y), we, be);
    float v3 = x[p3.x * 9 + f] + fmaf(__int_as_float(p3.y), we, be);
    float v4 = x[p4.x * 9 + f] + fmaf(__int_as_float(p4.y), we, be);
    float v5 = x[p5.x * 9 + f] + fmaf(__int_as_float(p5.y), we, be);
    float v6 = x[p6.x * 9 + f] + fmaf(__int_as_float(p6.y), we, be);
    float v7 = x[p7.x * 9 + f] + fmaf(__int_as_float(p7.y), we, be);
    acc += m0 ? fmaxf(v0, 0.f) : 0.f;
    acc += m1 ? fmaxf(v1, 0.f) : 0.f;
    acc += m2 ? fmaxf(v2, 0.f) : 0.f;
    acc += m3 ? fmaxf(v3, 0.f) : 0.f;
    acc += m4 ? fmaxf(v4, 0.f) : 0.f;
    acc += m5 ? fmaxf(v5, 0.f) : 0.f;
    acc += m6 ? fmaxf(v6, 0.f) : 0.f;
    acc += m7 ? fmaxf(v7, 0.f) : 0.f;
  }
  u1[node * 9 + f] = x[node * 9 + f] + acc;
}

// ---------------- Layer-2 aggregation: one wave/node; 8 edge-slots x 8 feature-chunks ----------------
// Two-tier predicated schedule (8-deep while >32 remain, 4-deep final), SCALAR f32 math.
// R6: packed f32x2 -> VGPR cliff (44->68, 144us). R9: NaN-pad mask-free -> stalls tripled.
// This exact form measured 83us @ VGPR 44, VALUBusy 79%. Node range [n_base, n_end):
// split into halves per launch purely so the rocprof top-5 can see the #2 kernel.
__global__ void __launch_bounds__(256) k_agg2(
    const __half* __restrict__ h1, const long long* __restrict__ csr,
    const int* __restrict__ noffs, const float* __restrict__ We2,
    const float* __restrict__ be2, float* __restrict__ u2, int n_base, int n_end) {
  int gt = blockIdx.x * TPB + threadIdx.x;
  int node = n_base + (gt >> 6);
  if (node >= n_end) return;
  int lane = gt & 63;
  int q = lane >> 3, c = lane & 7;
  float4 weA = *(const float4*)&We2[c * 8];
  float4 weB = *(const float4*)&We2[c * 8 + 4];
  float4 beA = *(const float4*)&be2[c * 8];
  float4 beB = *(const float4*)&be2[c * 8 + 4];
  int o0 = noffs[node], o1 = noffs[node + 1];
  float a0 = 0.f, a1 = 0.f, a2 = 0.f, a3 = 0.f, a4 = 0.f, a5 = 0.f, a6 = 0.f, a7 = 0.f;

#define AGG2_ACCM(pv, v, m)                                                  \
  {                                                                          \
    float ea = __int_as_float((int)(unsigned int)(((unsigned long long)(pv)) >> 32)); \
    float2 f0 = __half22float2((v).a), f1 = __half22float2((v).b);           \
    float2 f2 = __half22float2((v).c), f3 = __half22float2((v).d);           \
    a0 += (m) ? fmaxf(f0.x + fmaf(ea, weA.x, beA.x), 0.f) : 0.f;             \
    a1 += (m) ? fmaxf(f0.y + fmaf(ea, weA.y, beA.y), 0.f) : 0.f;             \
    a2 += (m) ? fmaxf(f1.x + fmaf(ea, weA.z, beA.z), 0.f) : 0.f;             \
    a3 += (m) ? fmaxf(f1.y + fmaf(ea, weA.w, beA.w), 0.f) : 0.f;             \
    a4 += (m) ? fmaxf(f2.x + fmaf(ea, weB.x, beB.x), 0.f) : 0.f;             \
    a5 += (m) ? fmaxf(f2.y + fmaf(ea, weB.y, beB.y), 0.f) : 0.f;             \
    a6 += (m) ? fmaxf(f3.x + fmaf(ea, weB.z, beB.z), 0.f) : 0.f;             \
    a7 += (m) ? fmaxf(f3.y + fmaf(ea, weB.w, beB.w), 0.f) : 0.f;             \
  }

  int e = o0;
  // 8-deep passes while more than one 32-edge tier remains
  if (o1 - e > 32) {
    int last = o1 - 1;
    do {
      long long pv0, pv1, pv2, pv3, pv4, pv5, pv6, pv7;
      bool m0, m1, m2, m3, m4, m5, m6, m7;
      {
        int i0 = e + q;      m0 = i0 < o1; i0 = m0 ? i0 : last;
        int i1 = e + 8 + q;  m1 = i1 < o1; i1 = m1 ? i1 : last;
        int i2 = e + 16 + q; m2 = i2 < o1; i2 = m2 ? i2 : last;
        int i3 = e + 24 + q; m3 = i3 < o1; i3 = m3 ? i3 : last;
        int i4 = e + 32 + q; m4 = i4 < o1; i4 = m4 ? i4 : last;
        int i5 = e + 40 + q; m5 = i5 < o1; i5 = m5 ? i5 : last;
        int i6 = e + 48 + q; m6 = i6 < o1; i6 = m6 ? i6 : last;
        int i7 = e + 56 + q; m7 = i7 < o1; i7 = m7 ? i7 : last;
        pv0 = __builtin_nontemporal_load(&csr[i0]);
        pv1 = __builtin_nontemporal_load(&csr[i1]);
        pv2 = __builtin_nontemporal_load(&csr[i2]);
        pv3 = __builtin_nontemporal_load(&csr[i3]);
        pv4 = __builtin_nontemporal_load(&csr[i4]);
        pv5 = __builtin_nontemporal_load(&csr[i5]);
        pv6 = __builtin_nontemporal_load(&csr[i6]);
        pv7 = __builtin_nontemporal_load(&csr[i7]);
      }
      h2x4 v0 = *(const h2x4*)(h1 + (size_t)(int)(unsigned int)(pv0 & 0xffffffffLL) * 64 + c * 8);
      h2x4 v1 = *(const h2x4*)(h1 + (size_t)(int)(unsigned int)(pv1 & 0xffffffffLL) * 64 + c * 8);
      h2x4 v2 = *(const h2x4*)(h1 + (size_t)(int)(unsigned int)(pv2 & 0xffffffffLL) * 64 + c * 8);
      h2x4 v3 = *(const h2x4*)(h1 + (size_t)(int)(unsigned int)(pv3 & 0xffffffffLL) * 64 + c * 8);
      h2x4 v4 = *(const h2x4*)(h1 + (size_t)(int)(unsigned int)(pv4 & 0xffffffffLL) * 64 + c * 8);
      h2x4 v5 = *(const h2x4*)(h1 + (size_t)(int)(unsigned int)(pv5 & 0xffffffffLL) * 64 + c * 8);
      h2x4 v6 = *(const h2x4*)(h1 + (size_t)(int)(unsigned int)(pv6 & 0xffffffffLL) * 64 + c * 8);
      h2x4 v7 = *(const h2x4*)(h1 + (size_t)(int)(unsigned int)(pv7 & 0xffffffffLL) * 64 + c * 8);
      AGG2_ACCM(pv0, v0, m0); AGG2_ACCM(pv1, v1, m1);
      AGG2_ACCM(pv2, v2, m2); AGG2_ACCM(pv3, v3, m3);
      AGG2_ACCM(pv4, v4, m4); AGG2_ACCM(pv5, v5, m5);
      AGG2_ACCM(pv6, v6, m6); AGG2_ACCM(pv7, v7, m7);
      e += 64;
    } while (o1 - e > 32);
  }
  // final tier: <=32 edges, 4-deep predicated
  if (e < o1) {
    int last = o1 - 1;
    int i0 = e + q;      bool m0 = i0 < o1; i0 = m0 ? i0 : last;
    int i1 = e + 8 + q;  bool m1 = i1 < o1; i1 = m1 ? i1 : last;
    int i2 = e + 16 + q; bool m2 = i2 < o1; i2 = m2 ? i2 : last;
    int i3 = e + 24 + q; bool m3 = i3 < o1; i3 = m3 ? i3 : last;
    long long pv0 = __builtin_nontemporal_load(&csr[i0]);
    long long pv1 = __builtin_nontemporal_load(&csr[i1]);
    long long pv2 = __builtin_nontemporal_load(&csr[i2]);
    long long pv3 = __builtin_nontemporal_load(&csr[i3]);
    h2x4 v0 = *(const h2x4*)(h1 + (size_t)(int)(unsigned int)(pv0 & 0xffffffffLL) * 64 + c * 8);
    h2x4 v1 = *(const h2x4*)(h1 + (size_t)(int)(unsigned int)(pv1 & 0xffffffffLL) * 64 + c * 8);
    h2x4 v2 = *(const h2x4*)(h1 + (size_t)(int)(unsigned int)(pv2 & 0xffffffffLL) * 64 + c * 8);
    h2x4 v3 = *(const h2x4*)(h1 + (size_t)(int)(unsigned int)(pv3 & 0xffffffffLL) * 64 + c * 8);
    AGG2_ACCM(pv0, v0, m0); AGG2_ACCM(pv1, v1, m1);
    AGG2_ACCM(pv2, v2, m2); AGG2_ACCM(pv3, v3, m3);
  }
#undef AGG2_ACCM

  a0 += __shfl_xor(a0, 8, 64); a0 += __shfl_xor(a0, 16, 64); a0 += __shfl_xor(a0, 32, 64);
  a1 += __shfl_xor(a1, 8, 64); a1 += __shfl_xor(a1, 16, 64); a1 += __shfl_xor(a1, 32, 64);
  a2 += __shfl_xor(a2, 8, 64); a2 += __shfl_xor(a2, 16, 64); a2 += __shfl_xor(a2, 32, 64);
  a3 += __shfl_xor(a3, 8, 64); a3 += __shfl_xor(a3, 16, 64); a3 += __shfl_xor(a3, 32, 64);
  a4 += __shfl_xor(a4, 8, 64); a4 += __shfl_xor(a4, 16, 64); a4 += __shfl_xor(a4, 32, 64);
  a5 += __shfl_xor(a5, 8, 64); a5 += __shfl_xor(a5, 16, 64); a5 += __shfl_xor(a5, 32, 64);
  a6 += __shfl_xor(a6, 8, 64); a6 += __shfl_xor(a6, 16, 64); a6 += __shfl_xor(a6, 32, 64);
  a7 += __shfl_xor(a7, 8, 64); a7 += __shfl_xor(a7, 16, 64); a7 += __shfl_xor(a7, 32, 64);

  if (q == 0) {
    h2x4 sf = *(const h2x4*)(h1 + (size_t)node * 64 + c * 8);
    float2 s0 = __half22float2(sf.a), s1 = __half22float2(sf.b);
    float2 s2 = __half22float2(sf.c), s3 = __half22float2(sf.d);
    float4 oA, oB;
    oA.x = s0.x + a0; oA.y = s0.y + a1; oA.z = s1.x + a2; oA.w = s1.y + a3;
    oB.x = s2.x + a4; oB.y = s2.y + a5; oB.z = s3.x + a6; oB.w = s3.y + a7;
    *(float4*)&u2[(size_t)node * 64 + c * 8] = oA;
    *(float4*)&u2[(size_t)node * 64 + c * 8 + 4] = oB;
  }
}

// ---------------- split-fp16 helpers for MFMA (f32-class accuracy) ----------------
__device__ __forceinline__ void splitf8(const float* v, f16x8& h, f16x8& l) {
#pragma unroll
  for (int j = 0; j < 8; ++j) {
    float x = v[j];
    f16 hh = (f16)x;
    h[j] = hh;
    l[j] = (f16)(x - (float)hh);
  }
}

// pack W [K][Nout] row-major into per-lane MFMA B-fragments (hi/lo planes).
__device__ __forceinline__ void pack_w(const float* __restrict__ W, int Ntiles, int nslots,
                                       f16* hi, f16* lo, int t) {
  int lane = t & 63;
  int kg = lane >> 4, m = lane & 15;
  int Nout = Ntiles * 16;
  for (int s = t >> 6; s < nslots; s += 4) {
    int ks = s / Ntiles, nt = s - ks * Ntiles;
    int kbase = ks * 32 + kg * 8;
    int n = nt * 16 + m;
    float v[8];
#pragma unroll
    for (int j = 0; j < 8; ++j) v[j] = W[(kbase + j) * Nout + n];
    f16x8 h, l;
    splitf8(v, h, l);
    *(f16x8*)&hi[(s * 64 + lane) * 8] = h;
    *(f16x8*)&lo[(s * 64 + lane) * 8] = l;
  }
}

// ---------------- Layer-1 MLP (9->64->64) via split-fp16 MFMA, fp16 output ----------------
__global__ void __launch_bounds__(256) k_mlp9(
    const float* __restrict__ uin, const float* __restrict__ Wa,
    const float* __restrict__ ba, const float* __restrict__ Wb,
    const float* __restrict__ bb, __half* __restrict__ hout, int N) {
  __shared__ __align__(16) f16 wf1h[2048], wf1l[2048];
  __shared__ __align__(16) f16 wf2h[4096], wf2l[4096];
  __shared__ float ls_z[64 * 65];
  __shared__ float ls_ba[64], ls_bb[64];
  const int t = threadIdx.x;
  const int n0 = blockIdx.x * 64;
  const int w = t >> 6, lane = t & 63;
  const int m = lane & 15, kg = lane >> 4;

  {
    int s = w;
    int n = s * 16 + m;
    float v[8];
#pragma unroll
    for (int j = 0; j < 8; ++j) {
      int k = kg * 8 + j;
      v[j] = (k < 9) ? Wa[k * 64 + n] : 0.f;
    }
    f16x8 h, l;
    splitf8(v, h, l);
    *(f16x8*)&wf1h[(s * 64 + lane) * 8] = h;
    *(f16x8*)&wf1l[(s * 64 + lane) * 8] = l;
  }
  pack_w(Wb, 4, 8, wf2h, wf2l, t);
  if (t < 64) { ls_ba[t] = ba[t]; ls_bb[t] = bb[t]; }
  __syncthreads();

  int row = min(n0 + w * 16 + m, N - 1);
  float av[8];
#pragma unroll
  for (int j = 0; j < 8; ++j) {
    int k = kg * 8 + j;
    av[j] = (k < 9) ? uin[(size_t)row * 9 + k] : 0.f;
  }
  f16x8 a0h, a0l, a1h, a1l;
  splitf8(av, a0h, a0l);

  f32x4 acc[4];
#pragma unroll
  for (int nt = 0; nt < 4; ++nt) { f32x4 z4 = {0.f, 0.f, 0.f, 0.f}; acc[nt] = z4; }
#pragma unroll
  for (int nt = 0; nt < 4; ++nt) {
    f16x8 bh = *(const f16x8*)&wf1h[(nt * 64 + lane) * 8];
    f16x8 bl = *(const f16x8*)&wf1l[(nt * 64 + lane) * 8];
    acc[nt] = MFMA16(a0h, bh, acc[nt]);
    acc[nt] = MFMA16(a0l, bh, acc[nt]);
    acc[nt] = MFMA16(a0h, bl, acc[nt]);
  }
#pragma unroll
  for (int nt = 0; nt < 4; ++nt)
#pragma unroll
    for (int r = 0; r < 4; ++r)
      ls_z[(w * 16 + kg * 4 + r) * 65 + nt * 16 + m] = fmaxf(acc[nt][r] + ls_ba[nt * 16 + m], 0.f);
  __syncthreads();

  const float* zr = &ls_z[(size_t)(w * 16 + m) * 65 + kg * 8];
  {
    float zv0[8], zv1[8];
#pragma unroll
    for (int j = 0; j < 8; ++j) { zv0[j] = zr[j]; zv1[j] = zr[32 + j]; }
    splitf8(zv0, a0h, a0l);
    splitf8(zv1, a1h, a1l);
  }
#pragma unroll
  for (int nt = 0; nt < 4; ++nt) { f32x4 z4 = {0.f, 0.f, 0.f, 0.f}; acc[nt] = z4; }
#pragma unroll
  for (int nt = 0; nt < 4; ++nt) {
#pragma unroll
    for (int ks = 0; ks < 2; ++ks) {
      int s = ks * 4 + nt;
      f16x8 bh = *(const f16x8*)&wf2h[(s * 64 + lane) * 8];
      f16x8 bl = *(const f16x8*)&wf2l[(s * 64 + lane) * 8];
      f16x8 ah = ks ? a1h : a0h;
      f16x8 al = ks ? a1l : a0l;
      acc[nt] = MFMA16(ah, bh, acc[nt]);
      acc[nt] = MFMA16(al, bh, acc[nt]);
      acc[nt] = MFMA16(ah, bl, acc[nt]);
    }
  }
#pragma unroll
  for (int nt = 0; nt < 4; ++nt)
#pragma unroll
    for (int r = 0; r < 4; ++r) {
      int node = n0 + w * 16 + kg * 4 + r;
      if (node < N)
        hout[(size_t)node * 64 + nt * 16 + m] =
            __float2half(fmaxf(acc[nt][r] + ls_bb[nt * 16 + m], 0.f));
    }
}

// ---------------- Layer-2 MLP (64->64->64) + readout via split-fp16 MFMA ----------------
__global__ void __launch_bounds__(256) k_mlp_ro(
    const float* __restrict__ uin, const float* __restrict__ Wa,
    const float* __restrict__ ba, const float* __restrict__ Wb,
    const float* __restrict__ bb, const float* __restrict__ Wr1,
    const float* __restrict__ br1, const float* __restrict__ Wr2,
    const float* __restrict__ br2, const int* __restrict__ tmask,
    float* __restrict__ pi, int N) {
  __shared__ __align__(16) f16 wf1h[4096], wf1l[4096];
  __shared__ __align__(16) f16 wf2h[4096], wf2l[4096];
  __shared__ __align__(16) f16 wfrh[2048], wfrl[2048];
  __shared__ float ls_z[64 * 65];
  __shared__ float ls_ba[64], ls_bb[64], ls_br1[32], ls_w2[32];
  const int t = threadIdx.x;
  const int n0 = blockIdx.x * 64;

  pack_w(Wa, 4, 8, wf1h, wf1l, t);
  pack_w(Wb, 4, 8, wf2h, wf2l, t);
  pack_w(Wr1, 2, 4, wfrh, wfrl, t);
  if (t < 64) { ls_ba[t] = ba[t]; ls_bb[t] = bb[t]; }
  else if (t < 96) { ls_br1[t - 64] = br1[t - 64]; ls_w2[t - 64] = Wr2[t - 64]; }
  __syncthreads();

  const int w = t >> 6, lane = t & 63;
  const int m = lane & 15, kg = lane >> 4;

  int row = n0 + w * 16 + m;
  row = min(row, N - 1);
  const float* ar = uin + (size_t)row * 64 + kg * 8;
  float av0[8], av1[8];
  {
    f32x4 p0 = *(const f32x4*)ar;
    f32x4 p1 = *(const f32x4*)(ar + 4);
    f32x4 p2 = *(const f32x4*)(ar + 32);
    f32x4 p3 = *(const f32x4*)(ar + 36);
#pragma unroll
    for (int j = 0; j < 4; ++j) {
      av0[j] = p0[j]; av0[4 + j] = p1[j];
      av1[j] = p2[j]; av1[4 + j] = p3[j];
    }
  }
  f16x8 a0h, a0l, a1h, a1l;
  splitf8(av0, a0h, a0l);
  splitf8(av1, a1h, a1l);

  f32x4 acc[4];
#pragma unroll
  for (int nt = 0; nt < 4; ++nt) { f32x4 z4 = {0.f, 0.f, 0.f, 0.f}; acc[nt] = z4; }
#pragma unroll
  for (int nt = 0; nt < 4; ++nt) {
#pragma unroll
    for (int ks = 0; ks < 2; ++ks) {
      int s = ks * 4 + nt;
      f16x8 bh = *(const f16x8*)&wf1h[(s * 64 + lane) * 8];
      f16x8 bl = *(const f16x8*)&wf1l[(s * 64 + lane) * 8];
      f16x8 ah = ks ? a1h : a0h;
      f16x8 al = ks ? a1l : a0l;
      acc[nt] = MFMA16(ah, bh, acc[nt]);
      acc[nt] = MFMA16(al, bh, acc[nt]);
      acc[nt] = MFMA16(ah, bl, acc[nt]);
    }
  }
#pragma unroll
  for (int nt = 0; nt < 4; ++nt)
#pragma unroll
    for (int r = 0; r < 4; ++r)
      ls_z[(w * 16 + kg * 4 + r) * 65 + nt * 16 + m] = fmaxf(acc[nt][r] + ls_ba[nt * 16 + m], 0.f);
  __syncthreads();

  const float* zr = &ls_z[(size_t)(w * 16 + m) * 65 + kg * 8];
  {
    float zv0[8], zv1[8];
#pragma unroll
    for (int j = 0; j < 8; ++j) { zv0[j] = zr[j]; zv1[j] = zr[32 + j]; }
    splitf8(zv0, a0h, a0l);
    splitf8(zv1, a1h, a1l);
  }
#pragma unroll
  for (int nt = 0; nt < 4; ++nt) { f32x4 z4 = {0.f, 0.f, 0.f, 0.f}; acc[nt] = z4; }
#pragma unroll
  for (int nt = 0; nt < 4; ++nt) {
#pragma unroll
    for (int ks = 0; ks < 2; ++ks) {
      int s = ks * 4 + nt;
      f16x8 bh = *(const f16x8*)&wf2h[(s * 64 + lane) * 8];
      f16x8 bl = *(const f16x8*)&wf2l[(s * 64 + lane) * 8];
      f16x8 ah = ks ? a1h : a0h;
      f16x8 al = ks ? a1l : a0l;
      acc[nt] = MFMA16(ah, bh, acc[nt]);
      acc[nt] = MFMA16(al, bh, acc[nt]);
      acc[nt] = MFMA16(ah, bl, acc[nt]);
    }
  }
  __syncthreads();
#pragma unroll
  for (int nt = 0; nt < 4; ++nt)
#pragma unroll
    for (int r = 0; r < 4; ++r)
      ls_z[(w * 16 + kg * 4 + r) * 65 + nt * 16 + m] = fmaxf(acc[nt][r] + ls_bb[nt * 16 + m], 0.f);
  __syncthreads();

  {
    float zv0[8], zv1[8];
#pragma unroll
    for (int j = 0; j < 8; ++j) { zv0[j] = zr[j]; zv1[j] = zr[32 + j]; }
    splitf8(zv0, a0h, a0l);
    splitf8(zv1, a1h, a1l);
  }
  f32x4 accr[2];
#pragma unroll
  for (int nt = 0; nt < 2; ++nt) { f32x4 z4 = {0.f, 0.f, 0.f, 0.f}; accr[nt] = z4; }
#pragma unroll
  for (int nt = 0; nt < 2; ++nt) {
#pragma unroll
    for (int ks = 0; ks < 2; ++ks) {
      int s = ks * 2 + nt;
      f16x8 bh = *(const f16x8*)&wfrh[(s * 64 + lane) * 8];
      f16x8 bl = *(const f16x8*)&wfrl[(s * 64 + lane) * 8];
      f16x8 ah = ks ? a1h : a0h;
      f16x8 al = ks ? a1l : a0l;
      accr[nt] = MFMA16(ah, bh, accr[nt]);
      accr[nt] = MFMA16(al, bh, accr[nt]);
      accr[nt] = MFMA16(ah, bl, accr[nt]);
    }
  }
  float b2 = br2[0];
#pragma unroll
  for (int r = 0; r < 4; ++r) {
    float v0 = fmaxf(accr[0][r] + ls_br1[m], 0.f) * ls_w2[m];
    float v1 = fmaxf(accr[1][r] + ls_br1[16 + m], 0.f) * ls_w2[16 + m];
    float tr = v0 + v1;
    tr += __shfl_xor(tr, 1, 64);
    tr += __shfl_xor(tr, 2, 64);
    tr += __shfl_xor(tr, 4, 64);
    tr += __shfl_xor(tr, 8, 64);
    if (m == 0) {
      int node = n0 + w * 16 + kg * 4 + r;
      if (node < N) {
        float sg = 1.f / (1.f + expf(-(tr + b2)));
        pi[node] = sg * (1.f - (float)tmask[node]);
      }
    }
  }
}

// ---------------- Group sums (batch sorted) ----------------
__global__ void k_grpsum(const float* __restrict__ pi, const float* __restrict__ c_cost,
                         const int* __restrict__ batch, float* __restrict__ exp_tot, int N) {
  __shared__ float lsf[256];
  __shared__ int lsi[256];
  int t = threadIdx.x;
  int i = blockIdx.x * TPB + t;
  bool valid = i < N;
  int g = valid ? batch[i] : 0;
  float v = valid ? pi[i] * c_cost[i] : 0.f;
  lsi[t] = valid ? g : 0x7fffffff;
  __syncthreads();
  for (int s = 128; s > 0; s >>= 1) { if (t < s) lsi[t] = min(lsi[t], lsi[t + s]); __syncthreads(); }
  int gmin = lsi[0];
  __syncthreads();
  lsi[t] = valid ? g : -1;
  __syncthreads();
  for (int s = 128; s > 0; s >>= 1) { if (t < s) lsi[t] = max(lsi[t], lsi[t + s]); __syncthreads(); }
  int gmax = lsi[0];
  __syncthreads();
  for (int gg = gmin; gg <= gmax; ++gg) {
    lsf[t] = (valid && g == gg) ? v : 0.f;
    __syncthreads();
    for (int s = 128; s > 0; s >>= 1) { if (t < s) lsf[t] += lsf[t + s]; __syncthreads(); }
    if (t == 0) atomicAdd(&exp_tot[gg], lsf[0]);
    __syncthreads();
  }
}

__global__ void k_final(const float* __restrict__ pi, const int* __restrict__ batch,
                        const float* __restrict__ B_total, const float* __restrict__ exp_tot,
                        float* __restrict__ out, int N) {
  int i = blockIdx.x * TPB + threadIdx.x;
  if (i < N) {
    int g = batch[i];
    float ratio = fminf(B_total[g] / (exp_tot[g] + 1e-12f), 1.f);
    out[i] = pi[i] * ratio;
  }
}

extern "C" void kernel_launch(void* const* d_in, const int* in_sizes, int n_in,
                              void* d_out, int out_size, void* d_ws, size_t ws_size,
                              hipStream_t stream) {
  const float* x     = (const float*)d_in[0];
  const int*   ei    = (const int*)d_in[1];
  const float* eattr = (const float*)d_in[2];
  const int*   batch = (const int*)d_in[3];
  const float* Btot  = (const float*)d_in[4];
  const int*   tmask = (const int*)d_in[5];
  const float* ccost = (const float*)d_in[6];
  const float* We1 = (const float*)d_in[7],  *be1 = (const float*)d_in[8];
  const float* W1a = (const float*)d_in[9],  *b1a = (const float*)d_in[10];
  const float* W1b = (const float*)d_in[11], *b1b = (const float*)d_in[12];
  const float* We2 = (const float*)d_in[13], *be2 = (const float*)d_in[14];
  const float* W2a = (const float*)d_in[15], *b2a = (const float*)d_in[16];
  const float* W2b = (const float*)d_in[17], *b2b = (const float*)d_in[18];
  const float* Wr1 = (const float*)d_in[19], *br1 = (const float*)d_in[20];
  const float* Wr2 = (const float*)d_in[21], *br2 = (const float*)d_in[22];
  float* out = (float*)d_out;

  const int N = in_sizes[0] / 9;
  const int E = in_sizes[2];
  const int G = in_sizes[4];
  const int* src = ei;
  const int* dst = ei + E;
  const int B = (N + (1 << BSHIFT) - 1) >> BSHIFT;  // 256-node bins
  const int nscan = B * P_BLOCKS;

  // workspace carve-up (4-byte elements)
  size_t cur = 0;
  auto alloc = [&](size_t elems) { size_t r = cur; cur += elems; cur = (cur + 63) & ~(size_t)63; return r; };
  char* wsb = (char*)d_ws;
  size_t o_exp    = alloc(G);             // zeroed
  size_t o_counts = alloc(nscan);
  size_t o_offs   = alloc(nscan + 1);
  size_t o_bsums  = alloc(256);
  size_t o_noffs  = alloc(N + 1);
  size_t o_csr    = alloc(2 * (size_t)E);
  size_t e_or_h   = (2 * (size_t)E > (size_t)N * 32) ? 2 * (size_t)E : (size_t)N * 32;
  size_t o_ebuf   = alloc(e_or_h);        // ebuf (dead after k_bsort) aliased with h1 (fp16)
  size_t o_u1     = alloc((size_t)N * 9);
  size_t o_u2     = alloc((size_t)N * 64);
  size_t o_pi     = alloc(N);
  (void)ws_size;

  float* exp_t  = (float*)wsb + o_exp;
  int*   counts = (int*)wsb + o_counts;
  int*   offs   = (int*)wsb + o_offs;
  int*   bsums  = (int*)wsb + o_bsums;
  int*   noffs  = (int*)wsb + o_noffs;
  int2*  csr    = (int2*)((int*)wsb + o_csr);
  int2*  ebuf   = (int2*)((int*)wsb + o_ebuf);
  __half* h1h   = (__half*)((int*)wsb + o_ebuf);  // alias: ebuf dead before h1 written
  float* u1     = (float*)wsb + o_u1;
  float* u2     = (float*)wsb + o_u2;
  float* pi     = (float*)wsb + o_pi;

  (void)hipMemsetAsync(exp_t, 0, (size_t)G * 4, stream);

  const int nb = (nscan + 1023) / 1024;

  k_bhist<<<P_BLOCKS, TPB, 0, stream>>>(dst, counts, E, B);
  k_scan_block<<<nb, TPB, 0, stream>>>(counts, offs, bsums, nscan);
  k_scan_mid<<<1, 256, 0, stream>>>(bsums, nb);
  k_scan_add<<<nb, TPB, 0, stream>>>(offs, bsums, nscan, E);
  k_bfill<<<P_BLOCKS, TPB, 0, stream>>>(src, dst, eattr, offs, ebuf, E, B);
  k_bsort<<<B, TPB, 0, stream>>>((const long long*)ebuf, offs, csr, noffs, N, E);

  k_agg1<<<((size_t)N * 16 + TPB - 1) / TPB, TPB, 0, stream>>>(x, csr, noffs, We1, be1, u1, N);
  k_mlp9<<<(N + 63) / 64, TPB, 0, stream>>>(u1, W1a, b1a, W1b, b1b, h1h, N);

  // agg2 split into two half-grids: bit-identical, lets rocprof top-5 reveal kernel #2
  int half = N / 2;
  k_agg2<<<((size_t)half * 64 + TPB - 1) / TPB, TPB, 0, stream>>>(
      h1h, (const long long*)csr, noffs, We2, be2, u2, 0, half);
  k_agg2<<<((size_t)(N - half) * 64 + TPB - 1) / TPB, TPB, 0, stream>>>(
      h1h, (const long long*)csr, noffs, We2, be2, u2, half, N);

  k_mlp_ro<<<(N + 63) / 64, TPB, 0, stream>>>(u2, W2a, b2a, W2b, b2b, Wr1, br1, Wr2, br2, tmask, pi, N);

  k_grpsum<<<(N + TPB - 1) / TPB, TPB, 0, stream>>>(pi, ccost, batch, exp_t, N);
  k_final<<<(N + TPB - 1) / TPB, TPB, 0, stream>>>(pi, batch, Btot, exp_t, out, N);
}

// Round 11
// 383.814 us; speedup vs baseline: 1.4738x; 1.0774x over previous
//
#include <hip/hip_runtime.h>
#include <hip/hip_fp16.h>
#include <math.h>

#define TPB 256
#define TPBF 1024         // big blocks for the latency-starved preprocessing kernels
#define P_BLOCKS 512
#define BSHIFT 8          // 256 nodes per bin
#define BINS_MAX 512      // >= ceil(100000/256)=391

struct alignas(8)  h2x2 { __half2 a, b; };
struct alignas(16) h2x4 { __half2 a, b, c, d; };

typedef _Float16 f16;
typedef __attribute__((ext_vector_type(8))) _Float16 f16x8;
typedef __attribute__((ext_vector_type(4))) float f32x4;

#define MFMA16(a, b, c) __builtin_amdgcn_mfma_f32_16x16x32_f16(a, b, c, 0, 0, 0)

// ---------------- bucketed histogram: counts[bin*P + blk] ----------------
// 1024-thread blocks: 512 blocks x 16 waves = 32 waves/CU (was 8 -> 25% occ cap, R10 PMC).
__global__ void __launch_bounds__(1024) k_bhist(const int* __restrict__ dst,
                                                int* __restrict__ counts, int E, int B) {
  __shared__ int h[BINS_MAX];
  int t = threadIdx.x, blk = blockIdx.x;
  for (int i = t; i < B; i += TPBF) h[i] = 0;
  __syncthreads();
  int chunk = (E + P_BLOCKS - 1) / P_BLOCKS;
  int s = blk * chunk, e = min(E, s + chunk);
  for (int i = s + t; i < e; i += TPBF)
    atomicAdd(&h[__builtin_nontemporal_load(&dst[i]) >> BSHIFT], 1);
  __syncthreads();
  for (int i = t; i < B; i += TPBF) counts[i * P_BLOCKS + blk] = h[i];
}

// ---------------- scan (1024 items/block) ----------------
__global__ void k_scan_block(const int* __restrict__ deg, int* __restrict__ offs,
                             int* __restrict__ bsums, int n) {
  __shared__ int lds[256];
  int t = threadIdx.x, b = blockIdx.x;
  int base = b * 1024 + t * 4;
  int v0 = (base + 0 < n) ? deg[base + 0] : 0;
  int v1 = (base + 1 < n) ? deg[base + 1] : 0;
  int v2 = (base + 2 < n) ? deg[base + 2] : 0;
  int v3 = (base + 3 < n) ? deg[base + 3] : 0;
  int s = v0 + v1 + v2 + v3;
  lds[t] = s;
  __syncthreads();
  int acc = s;
  for (int off = 1; off < 256; off <<= 1) {
    int x = (t >= off) ? lds[t - off] : 0;
    __syncthreads();
    acc += x;
    lds[t] = acc;
    __syncthreads();
  }
  int excl = acc - s;
  if (base + 0 < n) offs[base + 0] = excl;
  if (base + 1 < n) offs[base + 1] = excl + v0;
  if (base + 2 < n) offs[base + 2] = excl + v0 + v1;
  if (base + 3 < n) offs[base + 3] = excl + v0 + v1 + v2;
  if (t == 255) bsums[b] = acc;
}

__global__ void k_scan_mid(int* __restrict__ bsums, int nb) {
  __shared__ int lds[256];
  int t = threadIdx.x;
  int v = (t < nb) ? bsums[t] : 0;
  lds[t] = v;
  __syncthreads();
  int acc = v;
  for (int off = 1; off < 256; off <<= 1) {
    int x = (t >= off) ? lds[t - off] : 0;
    __syncthreads();
    acc += x;
    lds[t] = acc;
    __syncthreads();
  }
  if (t < nb) bsums[t] = acc - v;  // exclusive
}

__global__ void k_scan_add(int* __restrict__ offs, const int* __restrict__ bsums,
                           int n, int total) {
  int t = threadIdx.x, b = blockIdx.x;
  int add = bsums[b];
  int base = b * 1024 + t * 4;
#pragma unroll
  for (int j = 0; j < 4; ++j)
    if (base + j < n) offs[base + j] += add;
  if (b == 0 && t == 0) offs[n] = total;
}

// ---------------- fill: atomic-free (LDS cursors), streaming bin appends ----------------
// 1024-thread blocks (occupancy fix, R10 PMC: 19% occ, 0.9% VALU at 256 threads).
__global__ void __launch_bounds__(1024) k_bfill(const int* __restrict__ src,
                                                const int* __restrict__ dst,
                                                const float* __restrict__ attr,
                                                const int* __restrict__ offs,
                                                int2* __restrict__ ebuf, int E, int B) {
  __shared__ int cur[BINS_MAX];
  int t = threadIdx.x, blk = blockIdx.x;
  for (int i = t; i < B; i += TPBF) cur[i] = offs[i * P_BLOCKS + blk];
  __syncthreads();
  int chunk = (E + P_BLOCKS - 1) / P_BLOCKS;
  int s = blk * chunk, e = min(E, s + chunk);
#pragma unroll 4
  for (int i = s + t; i < e; i += TPBF) {
    int d = __builtin_nontemporal_load(&dst[i]);
    int sv = __builtin_nontemporal_load(&src[i]);
    float av = __builtin_nontemporal_load(&attr[i]);
    int bin = d >> BSHIFT;
    int pos = atomicAdd(&cur[bin], 1);
    ebuf[pos] = make_int2((sv << BSHIFT) | (d & ((1 << BSHIFT) - 1)), __float_as_int(av));
  }
}

// ---------------- per-bin counting sort -> dst-sorted csr + node offsets ----------------
// 1024-thread blocks; the 256-wide LDS scan is guarded (all threads reach barriers).
__global__ void __launch_bounds__(1024) k_bsort(const long long* __restrict__ ebuf,
                                                const int* __restrict__ offs,
                                                int2* __restrict__ csr,
                                                int* __restrict__ noffs,
                                                int N, int E) {
  __shared__ int hist[256];
  __shared__ int cursor[256];
  __shared__ int sc[256];
  int t = threadIdx.x, bkt = blockIdx.x;
  if (t < 256) hist[t] = 0;
  __syncthreads();
  int s = offs[bkt * P_BLOCKS], e = offs[(bkt + 1) * P_BLOCKS];
#pragma unroll 4
  for (int i = s + t; i < e; i += TPBF) {
    long long pv = __builtin_nontemporal_load(&ebuf[i]);
    int key = (int)(unsigned int)(pv & 0xffffffffLL);
    atomicAdd(&hist[key & 255], 1);
  }
  __syncthreads();
  int v = (t < 256) ? hist[t] : 0;
  int acc = v;
  if (t < 256) sc[t] = v;
  __syncthreads();
  for (int off = 1; off < 256; off <<= 1) {
    int x = (t >= off && t < 256) ? sc[t - off] : 0;
    __syncthreads();
    acc += x;
    if (t < 256) sc[t] = acc;
    __syncthreads();
  }
  if (t < 256) {
    int base = s + acc - v;  // exclusive within bucket
    cursor[t] = base;
    int n = (bkt << BSHIFT) + t;
    if (n < N) noffs[n] = base;
  }
  if (bkt == 0 && t == 0) noffs[N] = E;
  __syncthreads();
#pragma unroll 4
  for (int i = s + t; i < e; i += TPBF) {
    long long pv = __builtin_nontemporal_load(&ebuf[i]);
    int key = (int)(unsigned int)(pv & 0xffffffffLL);
    int attr = (int)(unsigned int)(((unsigned long long)pv) >> 32);
    int pos = atomicAdd(&cursor[key & 255], 1);
    csr[pos] = make_int2(((unsigned int)key) >> BSHIFT, attr);
  }
}

// ---------------- Layer-1 aggregation: 16 threads/node, f<9 active ----------------
// Predicated 8-edge passes (8 csr + 8 x-gathers in flight).
__global__ void __launch_bounds__(256) k_agg1(
    const float* __restrict__ x, const int2* __restrict__ csr,
    const int* __restrict__ noffs, const float* __restrict__ We1,
    const float* __restrict__ be1, float* __restrict__ u1, int N) {
  int t = blockIdx.x * TPB + threadIdx.x;
  int node = t >> 4, f = t & 15;
  if (node >= N || f >= 9) return;
  int o0 = noffs[node], o1 = noffs[node + 1];
  float we = We1[f], be = be1[f];
  float acc = 0.f;
  int last = o1 - 1;
  for (int e = o0; e < o1; e += 8) {
    int i0 = e;     bool m0 = i0 < o1; i0 = m0 ? i0 : last;
    int i1 = e + 1; bool m1 = i1 < o1; i1 = m1 ? i1 : last;
    int i2 = e + 2; bool m2 = i2 < o1; i2 = m2 ? i2 : last;
    int i3 = e + 3; bool m3 = i3 < o1; i3 = m3 ? i3 : last;
    int i4 = e + 4; bool m4 = i4 < o1; i4 = m4 ? i4 : last;
    int i5 = e + 5; bool m5 = i5 < o1; i5 = m5 ? i5 : last;
    int i6 = e + 6; bool m6 = i6 < o1; i6 = m6 ? i6 : last;
    int i7 = e + 7; bool m7 = i7 < o1; i7 = m7 ? i7 : last;
    int2 p0 = csr[i0], p1 = csr[i1], p2 = csr[i2], p3 = csr[i3];
    int2 p4 = csr[i4], p5 = csr[i5], p6 = csr[i6], p7 = csr[i7];
    float v0 = x[p0.x * 9 + f] + fmaf(__int_as_float(p0.y), we, be);
    float v1 = x[p1.x * 9 + f] + fmaf(__int_as_float(p1.y), we, be);
    float v2 = x[p2.x * 9 + f] + fmaf(__int_as_float(p2.y), we, be);
    float v3 = x[p3.x * 9 + f] + fmaf(__int_as_float(p3.y), we, be);
    float v4 = x[p4.x * 9 + f] + fmaf(__int_as_float(p4.y), we, be);
    float v5 = x[p5.x * 9 + f] + fmaf(__int_as_float(p5.y), we, be);
    float v6 = x[p6.x * 9 + f] + fmaf(__int_as_float(p6.y), we, be);
    float v7 = x[p7.x * 9 + f] + fmaf(__int_as_float(p7.y), we, be);
    acc += m0 ? fmaxf(v0, 0.f) : 0.f;
    acc += m1 ? fmaxf(v1, 0.f) : 0.f;
    acc += m2 ? fmaxf(v2, 0.f) : 0.f;
    acc += m3 ? fmaxf(v3, 0.f) : 0.f;
    acc += m4 ? fmaxf(v4, 0.f) : 0.f;
    acc += m5 ? fmaxf(v5, 0.f) : 0.f;
    acc += m6 ? fmaxf(v6, 0.f) : 0.f;
    acc += m7 ? fmaxf(v7, 0.f) : 0.f;
  }
  u1[node * 9 + f] = x[node * 9 + f] + acc;
}

// ---------------- Layer-2 aggregation: one wave/node; 8 edge-slots x 8 feature-chunks ----------------
// Two-tier predicated schedule (8-deep while >32 remain, 4-deep final), SCALAR f32 math.
// R6: packed f32x2 -> VGPR cliff (44->68, 144us). R9: NaN-pad mask-free -> stalls tripled.
// This exact form measured 83us @ VGPR 44, VALUBusy 79%.
__global__ void __launch_bounds__(256) k_agg2(
    const __half* __restrict__ h1, const long long* __restrict__ csr,
    const int* __restrict__ noffs, const float* __restrict__ We2,
    const float* __restrict__ be2, float* __restrict__ u2, int n_base, int n_end) {
  int gt = blockIdx.x * TPB + threadIdx.x;
  int node = n_base + (gt >> 6);
  if (node >= n_end) return;
  int lane = gt & 63;
  int q = lane >> 3, c = lane & 7;
  float4 weA = *(const float4*)&We2[c * 8];
  float4 weB = *(const float4*)&We2[c * 8 + 4];
  float4 beA = *(const float4*)&be2[c * 8];
  float4 beB = *(const float4*)&be2[c * 8 + 4];
  int o0 = noffs[node], o1 = noffs[node + 1];
  float a0 = 0.f, a1 = 0.f, a2 = 0.f, a3 = 0.f, a4 = 0.f, a5 = 0.f, a6 = 0.f, a7 = 0.f;

#define AGG2_ACCM(pv, v, m)                                                  \
  {                                                                          \
    float ea = __int_as_float((int)(unsigned int)(((unsigned long long)(pv)) >> 32)); \
    float2 f0 = __half22float2((v).a), f1 = __half22float2((v).b);           \
    float2 f2 = __half22float2((v).c), f3 = __half22float2((v).d);           \
    a0 += (m) ? fmaxf(f0.x + fmaf(ea, weA.x, beA.x), 0.f) : 0.f;             \
    a1 += (m) ? fmaxf(f0.y + fmaf(ea, weA.y, beA.y), 0.f) : 0.f;             \
    a2 += (m) ? fmaxf(f1.x + fmaf(ea, weA.z, beA.z), 0.f) : 0.f;             \
    a3 += (m) ? fmaxf(f1.y + fmaf(ea, weA.w, beA.w), 0.f) : 0.f;             \
    a4 += (m) ? fmaxf(f2.x + fmaf(ea, weB.x, beB.x), 0.f) : 0.f;             \
    a5 += (m) ? fmaxf(f2.y + fmaf(ea, weB.y, beB.y), 0.f) : 0.f;             \
    a6 += (m) ? fmaxf(f3.x + fmaf(ea, weB.z, beB.z), 0.f) : 0.f;             \
    a7 += (m) ? fmaxf(f3.y + fmaf(ea, weB.w, beB.w), 0.f) : 0.f;             \
  }

  int e = o0;
  // 8-deep passes while more than one 32-edge tier remains
  if (o1 - e > 32) {
    int last = o1 - 1;
    do {
      long long pv0, pv1, pv2, pv3, pv4, pv5, pv6, pv7;
      bool m0, m1, m2, m3, m4, m5, m6, m7;
      {
        int i0 = e + q;      m0 = i0 < o1; i0 = m0 ? i0 : last;
        int i1 = e + 8 + q;  m1 = i1 < o1; i1 = m1 ? i1 : last;
        int i2 = e + 16 + q; m2 = i2 < o1; i2 = m2 ? i2 : last;
        int i3 = e + 24 + q; m3 = i3 < o1; i3 = m3 ? i3 : last;
        int i4 = e + 32 + q; m4 = i4 < o1; i4 = m4 ? i4 : last;
        int i5 = e + 40 + q; m5 = i5 < o1; i5 = m5 ? i5 : last;
        int i6 = e + 48 + q; m6 = i6 < o1; i6 = m6 ? i6 : last;
        int i7 = e + 56 + q; m7 = i7 < o1; i7 = m7 ? i7 : last;
        pv0 = __builtin_nontemporal_load(&csr[i0]);
        pv1 = __builtin_nontemporal_load(&csr[i1]);
        pv2 = __builtin_nontemporal_load(&csr[i2]);
        pv3 = __builtin_nontemporal_load(&csr[i3]);
        pv4 = __builtin_nontemporal_load(&csr[i4]);
        pv5 = __builtin_nontemporal_load(&csr[i5]);
        pv6 = __builtin_nontemporal_load(&csr[i6]);
        pv7 = __builtin_nontemporal_load(&csr[i7]);
      }
      h2x4 v0 = *(const h2x4*)(h1 + (size_t)(int)(unsigned int)(pv0 & 0xffffffffLL) * 64 + c * 8);
      h2x4 v1 = *(const h2x4*)(h1 + (size_t)(int)(unsigned int)(pv1 & 0xffffffffLL) * 64 + c * 8);
      h2x4 v2 = *(const h2x4*)(h1 + (size_t)(int)(unsigned int)(pv2 & 0xffffffffLL) * 64 + c * 8);
      h2x4 v3 = *(const h2x4*)(h1 + (size_t)(int)(unsigned int)(pv3 & 0xffffffffLL) * 64 + c * 8);
      h2x4 v4 = *(const h2x4*)(h1 + (size_t)(int)(unsigned int)(pv4 & 0xffffffffLL) * 64 + c * 8);
      h2x4 v5 = *(const h2x4*)(h1 + (size_t)(int)(unsigned int)(pv5 & 0xffffffffLL) * 64 + c * 8);
      h2x4 v6 = *(const h2x4*)(h1 + (size_t)(int)(unsigned int)(pv6 & 0xffffffffLL) * 64 + c * 8);
      h2x4 v7 = *(const h2x4*)(h1 + (size_t)(int)(unsigned int)(pv7 & 0xffffffffLL) * 64 + c * 8);
      AGG2_ACCM(pv0, v0, m0); AGG2_ACCM(pv1, v1, m1);
      AGG2_ACCM(pv2, v2, m2); AGG2_ACCM(pv3, v3, m3);
      AGG2_ACCM(pv4, v4, m4); AGG2_ACCM(pv5, v5, m5);
      AGG2_ACCM(pv6, v6, m6); AGG2_ACCM(pv7, v7, m7);
      e += 64;
    } while (o1 - e > 32);
  }
  // final tier: <=32 edges, 4-deep predicated
  if (e < o1) {
    int last = o1 - 1;
    int i0 = e + q;      bool m0 = i0 < o1; i0 = m0 ? i0 : last;
    int i1 = e + 8 + q;  bool m1 = i1 < o1; i1 = m1 ? i1 : last;
    int i2 = e + 16 + q; bool m2 = i2 < o1; i2 = m2 ? i2 : last;
    int i3 = e + 24 + q; bool m3 = i3 < o1; i3 = m3 ? i3 : last;
    long long pv0 = __builtin_nontemporal_load(&csr[i0]);
    long long pv1 = __builtin_nontemporal_load(&csr[i1]);
    long long pv2 = __builtin_nontemporal_load(&csr[i2]);
    long long pv3 = __builtin_nontemporal_load(&csr[i3]);
    h2x4 v0 = *(const h2x4*)(h1 + (size_t)(int)(unsigned int)(pv0 & 0xffffffffLL) * 64 + c * 8);
    h2x4 v1 = *(const h2x4*)(h1 + (size_t)(int)(unsigned int)(pv1 & 0xffffffffLL) * 64 + c * 8);
    h2x4 v2 = *(const h2x4*)(h1 + (size_t)(int)(unsigned int)(pv2 & 0xffffffffLL) * 64 + c * 8);
    h2x4 v3 = *(const h2x4*)(h1 + (size_t)(int)(unsigned int)(pv3 & 0xffffffffLL) * 64 + c * 8);
    AGG2_ACCM(pv0, v0, m0); AGG2_ACCM(pv1, v1, m1);
    AGG2_ACCM(pv2, v2, m2); AGG2_ACCM(pv3, v3, m3);
  }
#undef AGG2_ACCM

  a0 += __shfl_xor(a0, 8, 64); a0 += __shfl_xor(a0, 16, 64); a0 += __shfl_xor(a0, 32, 64);
  a1 += __shfl_xor(a1, 8, 64); a1 += __shfl_xor(a1, 16, 64); a1 += __shfl_xor(a1, 32, 64);
  a2 += __shfl_xor(a2, 8, 64); a2 += __shfl_xor(a2, 16, 64); a2 += __shfl_xor(a2, 32, 64);
  a3 += __shfl_xor(a3, 8, 64); a3 += __shfl_xor(a3, 16, 64); a3 += __shfl_xor(a3, 32, 64);
  a4 += __shfl_xor(a4, 8, 64); a4 += __shfl_xor(a4, 16, 64); a4 += __shfl_xor(a4, 32, 64);
  a5 += __shfl_xor(a5, 8, 64); a5 += __shfl_xor(a5, 16, 64); a5 += __shfl_xor(a5, 32, 64);
  a6 += __shfl_xor(a6, 8, 64); a6 += __shfl_xor(a6, 16, 64); a6 += __shfl_xor(a6, 32, 64);
  a7 += __shfl_xor(a7, 8, 64); a7 += __shfl_xor(a7, 16, 64); a7 += __shfl_xor(a7, 32, 64);

  if (q == 0) {
    h2x4 sf = *(const h2x4*)(h1 + (size_t)node * 64 + c * 8);
    float2 s0 = __half22float2(sf.a), s1 = __half22float2(sf.b);
    float2 s2 = __half22float2(sf.c), s3 = __half22float2(sf.d);
    float4 oA, oB;
    oA.x = s0.x + a0; oA.y = s0.y + a1; oA.z = s1.x + a2; oA.w = s1.y + a3;
    oB.x = s2.x + a4; oB.y = s2.y + a5; oB.z = s3.x + a6; oB.w = s3.y + a7;
    *(float4*)&u2[(size_t)node * 64 + c * 8] = oA;
    *(float4*)&u2[(size_t)node * 64 + c * 8 + 4] = oB;
  }
}

// ---------------- split-fp16 helpers for MFMA (f32-class accuracy) ----------------
__device__ __forceinline__ void splitf8(const float* v, f16x8& h, f16x8& l) {
#pragma unroll
  for (int j = 0; j < 8; ++j) {
    float x = v[j];
    f16 hh = (f16)x;
    h[j] = hh;
    l[j] = (f16)(x - (float)hh);
  }
}

// pack W [K][Nout] row-major into per-lane MFMA B-fragments (hi/lo planes).
__device__ __forceinline__ void pack_w(const float* __restrict__ W, int Ntiles, int nslots,
                                       f16* hi, f16* lo, int t) {
  int lane = t & 63;
  int kg = lane >> 4, m = lane & 15;
  int Nout = Ntiles * 16;
  for (int s = t >> 6; s < nslots; s += 4) {
    int ks = s / Ntiles, nt = s - ks * Ntiles;
    int kbase = ks * 32 + kg * 8;
    int n = nt * 16 + m;
    float v[8];
#pragma unroll
    for (int j = 0; j < 8; ++j) v[j] = W[(kbase + j) * Nout + n];
    f16x8 h, l;
    splitf8(v, h, l);
    *(f16x8*)&hi[(s * 64 + lane) * 8] = h;
    *(f16x8*)&lo[(s * 64 + lane) * 8] = l;
  }
}

// ---------------- Layer-1 MLP (9->64->64) via split-fp16 MFMA, fp16 output ----------------
__global__ void __launch_bounds__(256) k_mlp9(
    const float* __restrict__ uin, const float* __restrict__ Wa,
    const float* __restrict__ ba, const float* __restrict__ Wb,
    const float* __restrict__ bb, __half* __restrict__ hout, int N) {
  __shared__ __align__(16) f16 wf1h[2048], wf1l[2048];
  __shared__ __align__(16) f16 wf2h[4096], wf2l[4096];
  __shared__ float ls_z[64 * 65];
  __shared__ float ls_ba[64], ls_bb[64];
  const int t = threadIdx.x;
  const int n0 = blockIdx.x * 64;
  const int w = t >> 6, lane = t & 63;
  const int m = lane & 15, kg = lane >> 4;

  {
    int s = w;
    int n = s * 16 + m;
    float v[8];
#pragma unroll
    for (int j = 0; j < 8; ++j) {
      int k = kg * 8 + j;
      v[j] = (k < 9) ? Wa[k * 64 + n] : 0.f;
    }
    f16x8 h, l;
    splitf8(v, h, l);
    *(f16x8*)&wf1h[(s * 64 + lane) * 8] = h;
    *(f16x8*)&wf1l[(s * 64 + lane) * 8] = l;
  }
  pack_w(Wb, 4, 8, wf2h, wf2l, t);
  if (t < 64) { ls_ba[t] = ba[t]; ls_bb[t] = bb[t]; }
  __syncthreads();

  int row = min(n0 + w * 16 + m, N - 1);
  float av[8];
#pragma unroll
  for (int j = 0; j < 8; ++j) {
    int k = kg * 8 + j;
    av[j] = (k < 9) ? uin[(size_t)row * 9 + k] : 0.f;
  }
  f16x8 a0h, a0l, a1h, a1l;
  splitf8(av, a0h, a0l);

  f32x4 acc[4];
#pragma unroll
  for (int nt = 0; nt < 4; ++nt) { f32x4 z4 = {0.f, 0.f, 0.f, 0.f}; acc[nt] = z4; }
#pragma unroll
  for (int nt = 0; nt < 4; ++nt) {
    f16x8 bh = *(const f16x8*)&wf1h[(nt * 64 + lane) * 8];
    f16x8 bl = *(const f16x8*)&wf1l[(nt * 64 + lane) * 8];
    acc[nt] = MFMA16(a0h, bh, acc[nt]);
    acc[nt] = MFMA16(a0l, bh, acc[nt]);
    acc[nt] = MFMA16(a0h, bl, acc[nt]);
  }
#pragma unroll
  for (int nt = 0; nt < 4; ++nt)
#pragma unroll
    for (int r = 0; r < 4; ++r)
      ls_z[(w * 16 + kg * 4 + r) * 65 + nt * 16 + m] = fmaxf(acc[nt][r] + ls_ba[nt * 16 + m], 0.f);
  __syncthreads();

  const float* zr = &ls_z[(size_t)(w * 16 + m) * 65 + kg * 8];
  {
    float zv0[8], zv1[8];
#pragma unroll
    for (int j = 0; j < 8; ++j) { zv0[j] = zr[j]; zv1[j] = zr[32 + j]; }
    splitf8(zv0, a0h, a0l);
    splitf8(zv1, a1h, a1l);
  }
#pragma unroll
  for (int nt = 0; nt < 4; ++nt) { f32x4 z4 = {0.f, 0.f, 0.f, 0.f}; acc[nt] = z4; }
#pragma unroll
  for (int nt = 0; nt < 4; ++nt) {
#pragma unroll
    for (int ks = 0; ks < 2; ++ks) {
      int s = ks * 4 + nt;
      f16x8 bh = *(const f16x8*)&wf2h[(s * 64 + lane) * 8];
      f16x8 bl = *(const f16x8*)&wf2l[(s * 64 + lane) * 8];
      f16x8 ah = ks ? a1h : a0h;
      f16x8 al = ks ? a1l : a0l;
      acc[nt] = MFMA16(ah, bh, acc[nt]);
      acc[nt] = MFMA16(al, bh, acc[nt]);
      acc[nt] = MFMA16(ah, bl, acc[nt]);
    }
  }
#pragma unroll
  for (int nt = 0; nt < 4; ++nt)
#pragma unroll
    for (int r = 0; r < 4; ++r) {
      int node = n0 + w * 16 + kg * 4 + r;
      if (node < N)
        hout[(size_t)node * 64 + nt * 16 + m] =
            __float2half(fmaxf(acc[nt][r] + ls_bb[nt * 16 + m], 0.f));
    }
}

// ---------------- Layer-2 MLP (64->64->64) + readout via split-fp16 MFMA ----------------
__global__ void __launch_bounds__(256) k_mlp_ro(
    const float* __restrict__ uin, const float* __restrict__ Wa,
    const float* __restrict__ ba, const float* __restrict__ Wb,
    const float* __restrict__ bb, const float* __restrict__ Wr1,
    const float* __restrict__ br1, const float* __restrict__ Wr2,
    const float* __restrict__ br2, const int* __restrict__ tmask,
    float* __restrict__ pi, int N) {
  __shared__ __align__(16) f16 wf1h[4096], wf1l[4096];
  __shared__ __align__(16) f16 wf2h[4096], wf2l[4096];
  __shared__ __align__(16) f16 wfrh[2048], wfrl[2048];
  __shared__ float ls_z[64 * 65];
  __shared__ float ls_ba[64], ls_bb[64], ls_br1[32], ls_w2[32];
  const int t = threadIdx.x;
  const int n0 = blockIdx.x * 64;

  pack_w(Wa, 4, 8, wf1h, wf1l, t);
  pack_w(Wb, 4, 8, wf2h, wf2l, t);
  pack_w(Wr1, 2, 4, wfrh, wfrl, t);
  if (t < 64) { ls_ba[t] = ba[t]; ls_bb[t] = bb[t]; }
  else if (t < 96) { ls_br1[t - 64] = br1[t - 64]; ls_w2[t - 64] = Wr2[t - 64]; }
  __syncthreads();

  const int w = t >> 6, lane = t & 63;
  const int m = lane & 15, kg = lane >> 4;

  int row = n0 + w * 16 + m;
  row = min(row, N - 1);
  const float* ar = uin + (size_t)row * 64 + kg * 8;
  float av0[8], av1[8];
  {
    f32x4 p0 = *(const f32x4*)ar;
    f32x4 p1 = *(const f32x4*)(ar + 4);
    f32x4 p2 = *(const f32x4*)(ar + 32);
    f32x4 p3 = *(const f32x4*)(ar + 36);
#pragma unroll
    for (int j = 0; j < 4; ++j) {
      av0[j] = p0[j]; av0[4 + j] = p1[j];
      av1[j] = p2[j]; av1[4 + j] = p3[j];
    }
  }
  f16x8 a0h, a0l, a1h, a1l;
  splitf8(av0, a0h, a0l);
  splitf8(av1, a1h, a1l);

  f32x4 acc[4];
#pragma unroll
  for (int nt = 0; nt < 4; ++nt) { f32x4 z4 = {0.f, 0.f, 0.f, 0.f}; acc[nt] = z4; }
#pragma unroll
  for (int nt = 0; nt < 4; ++nt) {
#pragma unroll
    for (int ks = 0; ks < 2; ++ks) {
      int s = ks * 4 + nt;
      f16x8 bh = *(const f16x8*)&wf1h[(s * 64 + lane) * 8];
      f16x8 bl = *(const f16x8*)&wf1l[(s * 64 + lane) * 8];
      f16x8 ah = ks ? a1h : a0h;
      f16x8 al = ks ? a1l : a0l;
      acc[nt] = MFMA16(ah, bh, acc[nt]);
      acc[nt] = MFMA16(al, bh, acc[nt]);
      acc[nt] = MFMA16(ah, bl, acc[nt]);
    }
  }
#pragma unroll
  for (int nt = 0; nt < 4; ++nt)
#pragma unroll
    for (int r = 0; r < 4; ++r)
      ls_z[(w * 16 + kg * 4 + r) * 65 + nt * 16 + m] = fmaxf(acc[nt][r] + ls_ba[nt * 16 + m], 0.f);
  __syncthreads();

  const float* zr = &ls_z[(size_t)(w * 16 + m) * 65 + kg * 8];
  {
    float zv0[8], zv1[8];
#pragma unroll
    for (int j = 0; j < 8; ++j) { zv0[j] = zr[j]; zv1[j] = zr[32 + j]; }
    splitf8(zv0, a0h, a0l);
    splitf8(zv1, a1h, a1l);
  }
#pragma unroll
  for (int nt = 0; nt < 4; ++nt) { f32x4 z4 = {0.f, 0.f, 0.f, 0.f}; acc[nt] = z4; }
#pragma unroll
  for (int nt = 0; nt < 4; ++nt) {
#pragma unroll
    for (int ks = 0; ks < 2; ++ks) {
      int s = ks * 4 + nt;
      f16x8 bh = *(const f16x8*)&wf2h[(s * 64 + lane) * 8];
      f16x8 bl = *(const f16x8*)&wf2l[(s * 64 + lane) * 8];
      f16x8 ah = ks ? a1h : a0h;
      f16x8 al = ks ? a1l : a0l;
      acc[nt] = MFMA16(ah, bh, acc[nt]);
      acc[nt] = MFMA16(al, bh, acc[nt]);
      acc[nt] = MFMA16(ah, bl, acc[nt]);
    }
  }
  __syncthreads();
#pragma unroll
  for (int nt = 0; nt < 4; ++nt)
#pragma unroll
    for (int r = 0; r < 4; ++r)
      ls_z[(w * 16 + kg * 4 + r) * 65 + nt * 16 + m] = fmaxf(acc[nt][r] + ls_bb[nt * 16 + m], 0.f);
  __syncthreads();

  {
    float zv0[8], zv1[8];
#pragma unroll
    for (int j = 0; j < 8; ++j) { zv0[j] = zr[j]; zv1[j] = zr[32 + j]; }
    splitf8(zv0, a0h, a0l);
    splitf8(zv1, a1h, a1l);
  }
  f32x4 accr[2];
#pragma unroll
  for (int nt = 0; nt < 2; ++nt) { f32x4 z4 = {0.f, 0.f, 0.f, 0.f}; accr[nt] = z4; }
#pragma unroll
  for (int nt = 0; nt < 2; ++nt) {
#pragma unroll
    for (int ks = 0; ks < 2; ++ks) {
      int s = ks * 2 + nt;
      f16x8 bh = *(const f16x8*)&wfrh[(s * 64 + lane) * 8];
      f16x8 bl = *(const f16x8*)&wfrl[(s * 64 + lane) * 8];
      f16x8 ah = ks ? a1h : a0h;
      f16x8 al = ks ? a1l : a0l;
      accr[nt] = MFMA16(ah, bh, accr[nt]);
      accr[nt] = MFMA16(al, bh, accr[nt]);
      accr[nt] = MFMA16(ah, bl, accr[nt]);
    }
  }
  float b2 = br2[0];
#pragma unroll
  for (int r = 0; r < 4; ++r) {
    float v0 = fmaxf(accr[0][r] + ls_br1[m], 0.f) * ls_w2[m];
    float v1 = fmaxf(accr[1][r] + ls_br1[16 + m], 0.f) * ls_w2[16 + m];
    float tr = v0 + v1;
    tr += __shfl_xor(tr, 1, 64);
    tr += __shfl_xor(tr, 2, 64);
    tr += __shfl_xor(tr, 4, 64);
    tr += __shfl_xor(tr, 8, 64);
    if (m == 0) {
      int node = n0 + w * 16 + kg * 4 + r;
      if (node < N) {
        float sg = 1.f / (1.f + expf(-(tr + b2)));
        pi[node] = sg * (1.f - (float)tmask[node]);
      }
    }
  }
}

// ---------------- Group sums (batch sorted) ----------------
__global__ void k_grpsum(const float* __restrict__ pi, const float* __restrict__ c_cost,
                         const int* __restrict__ batch, float* __restrict__ exp_tot, int N) {
  __shared__ float lsf[256];
  __shared__ int lsi[256];
  int t = threadIdx.x;
  int i = blockIdx.x * TPB + t;
  bool valid = i < N;
  int g = valid ? batch[i] : 0;
  float v = valid ? pi[i] * c_cost[i] : 0.f;
  lsi[t] = valid ? g : 0x7fffffff;
  __syncthreads();
  for (int s = 128; s > 0; s >>= 1) { if (t < s) lsi[t] = min(lsi[t], lsi[t + s]); __syncthreads(); }
  int gmin = lsi[0];
  __syncthreads();
  lsi[t] = valid ? g : -1;
  __syncthreads();
  for (int s = 128; s > 0; s >>= 1) { if (t < s) lsi[t] = max(lsi[t], lsi[t + s]); __syncthreads(); }
  int gmax = lsi[0];
  __syncthreads();
  for (int gg = gmin; gg <= gmax; ++gg) {
    lsf[t] = (valid && g == gg) ? v : 0.f;
    __syncthreads();
    for (int s = 128; s > 0; s >>= 1) { if (t < s) lsf[t] += lsf[t + s]; __syncthreads(); }
    if (t == 0) atomicAdd(&exp_tot[gg], lsf[0]);
    __syncthreads();
  }
}

__global__ void k_final(const float* __restrict__ pi, const int* __restrict__ batch,
                        const float* __restrict__ B_total, const float* __restrict__ exp_tot,
                        float* __restrict__ out, int N) {
  int i = blockIdx.x * TPB + threadIdx.x;
  if (i < N) {
    int g = batch[i];
    float ratio = fminf(B_total[g] / (exp_tot[g] + 1e-12f), 1.f);
    out[i] = pi[i] * ratio;
  }
}

extern "C" void kernel_launch(void* const* d_in, const int* in_sizes, int n_in,
                              void* d_out, int out_size, void* d_ws, size_t ws_size,
                              hipStream_t stream) {
  const float* x     = (const float*)d_in[0];
  const int*   ei    = (const int*)d_in[1];
  const float* eattr = (const float*)d_in[2];
  const int*   batch = (const int*)d_in[3];
  const float* Btot  = (const float*)d_in[4];
  const int*   tmask = (const int*)d_in[5];
  const float* ccost = (const float*)d_in[6];
  const float* We1 = (const float*)d_in[7],  *be1 = (const float*)d_in[8];
  const float* W1a = (const float*)d_in[9],  *b1a = (const float*)d_in[10];
  const float* W1b = (const float*)d_in[11], *b1b = (const float*)d_in[12];
  const float* We2 = (const float*)d_in[13], *be2 = (const float*)d_in[14];
  const float* W2a = (const float*)d_in[15], *b2a = (const float*)d_in[16];
  const float* W2b = (const float*)d_in[17], *b2b = (const float*)d_in[18];
  const float* Wr1 = (const float*)d_in[19], *br1 = (const float*)d_in[20];
  const float* Wr2 = (const float*)d_in[21], *br2 = (const float*)d_in[22];
  float* out = (float*)d_out;

  const int N = in_sizes[0] / 9;
  const int E = in_sizes[2];
  const int G = in_sizes[4];
  const int* src = ei;
  const int* dst = ei + E;
  const int B = (N + (1 << BSHIFT) - 1) >> BSHIFT;  // 256-node bins
  const int nscan = B * P_BLOCKS;

  // workspace carve-up (4-byte elements)
  size_t cur = 0;
  auto alloc = [&](size_t elems) { size_t r = cur; cur += elems; cur = (cur + 63) & ~(size_t)63; return r; };
  char* wsb = (char*)d_ws;
  size_t o_exp    = alloc(G);             // zeroed
  size_t o_counts = alloc(nscan);
  size_t o_offs   = alloc(nscan + 1);
  size_t o_bsums  = alloc(256);
  size_t o_noffs  = alloc(N + 1);
  size_t o_csr    = alloc(2 * (size_t)E);
  size_t e_or_h   = (2 * (size_t)E > (size_t)N * 32) ? 2 * (size_t)E : (size_t)N * 32;
  size_t o_ebuf   = alloc(e_or_h);        // ebuf (dead after k_bsort) aliased with h1 (fp16)
  size_t o_u1     = alloc((size_t)N * 9);
  size_t o_u2     = alloc((size_t)N * 64);
  size_t o_pi     = alloc(N);
  (void)ws_size;

  float* exp_t  = (float*)wsb + o_exp;
  int*   counts = (int*)wsb + o_counts;
  int*   offs   = (int*)wsb + o_offs;
  int*   bsums  = (int*)wsb + o_bsums;
  int*   noffs  = (int*)wsb + o_noffs;
  int2*  csr    = (int2*)((int*)wsb + o_csr);
  int2*  ebuf   = (int2*)((int*)wsb + o_ebuf);
  __half* h1h   = (__half*)((int*)wsb + o_ebuf);  // alias: ebuf dead before h1 written
  float* u1     = (float*)wsb + o_u1;
  float* u2     = (float*)wsb + o_u2;
  float* pi     = (float*)wsb + o_pi;

  (void)hipMemsetAsync(exp_t, 0, (size_t)G * 4, stream);

  const int nb = (nscan + 1023) / 1024;

  k_bhist<<<P_BLOCKS, TPBF, 0, stream>>>(dst, counts, E, B);
  k_scan_block<<<nb, TPB, 0, stream>>>(counts, offs, bsums, nscan);
  k_scan_mid<<<1, 256, 0, stream>>>(bsums, nb);
  k_scan_add<<<nb, TPB, 0, stream>>>(offs, bsums, nscan, E);
  k_bfill<<<P_BLOCKS, TPBF, 0, stream>>>(src, dst, eattr, offs, ebuf, E, B);
  k_bsort<<<B, TPBF, 0, stream>>>((const long long*)ebuf, offs, csr, noffs, N, E);

  k_agg1<<<((size_t)N * 16 + TPB - 1) / TPB, TPB, 0, stream>>>(x, csr, noffs, We1, be1, u1, N);
  k_mlp9<<<(N + 63) / 64, TPB, 0, stream>>>(u1, W1a, b1a, W1b, b1b, h1h, N);

  k_agg2<<<((size_t)N * 64 + TPB - 1) / TPB, TPB, 0, stream>>>(
      h1h, (const long long*)csr, noffs, We2, be2, u2, 0, N);

  k_mlp_ro<<<(N + 63) / 64, TPB, 0, stream>>>(u2, W2a, b2a, W2b, b2b, Wr1, br1, Wr2, br2, tmask, pi, N);

  k_grpsum<<<(N + TPB - 1) / TPB, TPB, 0, stream>>>(pi, ccost, batch, exp_t, N);
  k_final<<<(N + TPB - 1) / TPB, TPB, 0, stream>>>(pi, batch, Btot, exp_t, out, N);
}